// Round 1
// 1518.524 us; speedup vs baseline: 1.0102x; 1.0102x over previous
//
#include <hip/hip_runtime.h>
#include <cstdint>

#define HD 1024
#define INNER 2048
#define NTOK 2048
#define SEQL 1024
#define SDIM 16
#define DTR 64
#define VDIM 32000
#define FFN 2048
#define EPSV 1e-5f
#define SLOT_CAP 5120
#define MAX_TILES 40
#define NCH 32
#define CLEN 32

typedef __attribute__((ext_vector_type(8))) short short8;
typedef __attribute__((ext_vector_type(4))) float f32x4;

__device__ __forceinline__ unsigned short f2bf(float f){
  unsigned int u = __float_as_uint(f);
  u += 0x7FFF + ((u >> 16) & 1);
  return (unsigned short)(u >> 16);
}
__device__ __forceinline__ float sigm(float x){ return 1.f/(1.f+__expf(-x)); }

__device__ __forceinline__ void gload16(const unsigned short* g, unsigned short* l){
  __builtin_amdgcn_global_load_lds(
    (const __attribute__((address_space(1))) unsigned int*)g,
    (__attribute__((address_space(3))) unsigned int*)l, 16, 0, 0);
}

__device__ __forceinline__ float block_sum(float v, float* sb){
  #pragma unroll
  for (int m=32;m>=1;m>>=1) v += __shfl_xor(v, m, 64);
  int lane = threadIdx.x & 63, w = threadIdx.x >> 6;
  if (lane==0) sb[w]=v;
  __syncthreads();
  float s = sb[0]+sb[1]+sb[2]+sb[3];
  __syncthreads();
  return s;
}

// ---------------- embed + rms0 ----------------
__global__ __launch_bounds__(256) void embed_rms_k(
  const int* __restrict__ ids, const float* __restrict__ emb,
  const float* __restrict__ n0w, float* __restrict__ x, float* __restrict__ xn)
{
  __shared__ float sb[4];
  int tok = blockIdx.x, t = threadIdx.x;
  int id = ids[tok];
  float4 v = *(const float4*)(emb + (size_t)id*HD + t*4);
  *(float4*)(x + (size_t)tok*HD + t*4) = v;
  float tot = block_sum(v.x*v.x+v.y*v.y+v.z*v.z+v.w*v.w, sb);
  float rs = rsqrtf(tot/(float)HD + EPSV);
  float4 w = *(const float4*)(n0w + t*4);
  float4 o; o.x=v.x*rs*w.x; o.y=v.y*rs*w.y; o.z=v.z*rs*w.z; o.w=v.w*rs*w.w;
  *(float4*)(xn + (size_t)tok*HD + t*4) = o;
}

// ---------------- generic fp32 GEMM: C[M,N] = A[M,K(lda)] * B[N,K]^T ----------------
template<int EPI>
__global__ __launch_bounds__(256) void gemm_f32k(
  const float* __restrict__ A, int lda,
  const float* __restrict__ B,
  float* __restrict__ C, int ldc,
  int N, int K, const float* __restrict__ bias)
{
  __shared__ float As[16][68];
  __shared__ float Bs[16][68];
  int m0 = blockIdx.y*64, n0 = blockIdx.x*64;
  int t = threadIdx.x, tm = t & 15, tn = t >> 4;
  float acc[4][4] = {};
  int srow = t >> 2, skq = (t & 3) * 4;
  const float* arow = A + (size_t)(m0 + srow)*lda + skq;
  int nrow = n0 + srow;
  const float* brow = B + (size_t)nrow*K + skq;
  bool bok = nrow < N;
  for (int k0 = 0; k0 < K; k0 += 16) {
    float4 a = *(const float4*)(arow + k0);
    float4 b = bok ? *(const float4*)(brow + k0) : make_float4(0.f,0.f,0.f,0.f);
    __syncthreads();
    As[skq+0][srow]=a.x; As[skq+1][srow]=a.y; As[skq+2][srow]=a.z; As[skq+3][srow]=a.w;
    Bs[skq+0][srow]=b.x; Bs[skq+1][srow]=b.y; Bs[skq+2][srow]=b.z; Bs[skq+3][srow]=b.w;
    __syncthreads();
    #pragma unroll
    for (int k=0;k<16;k++){
      const float4 av = *(const float4*)&As[k][tm*4];
      const float4 bv = *(const float4*)&Bs[k][tn*4];
      float am[4] = {av.x, av.y, av.z, av.w};
      float bn[4] = {bv.x, bv.y, bv.z, bv.w};
      #pragma unroll
      for (int i=0;i<4;i++)
        #pragma unroll
        for (int j=0;j<4;j++)
          acc[i][j] += am[i]*bn[j];
    }
  }
  #pragma unroll
  for (int i=0;i<4;i++){
    int row = m0 + tm*4 + i;
    #pragma unroll
    for (int j=0;j<4;j++){
      int col = n0 + tn*4 + j;
      if (col < N){
        float v = acc[i][j];
        if (EPI==1){ v += bias[col]; v = (v > 20.f) ? v : log1pf(expf(v)); }
        if (EPI==2){ v += C[(size_t)row*ldc + col]; }
        C[(size_t)row*ldc + col] = v;
      }
    }
  }
}

// ---------------- causal depthwise conv (K=4) + silu ----------------
__global__ __launch_bounds__(256) void conv_silu_k(
  const float* __restrict__ proj, const float* __restrict__ cw,
  const float* __restrict__ cb, float* __restrict__ uc)
{
  int idx = blockIdx.x*256 + threadIdx.x;     // over B*L*INNER
  int c = idx & (INNER-1);
  int l = (idx >> 11) & (SEQL-1);
  int b = idx >> 21;
  float s = cb[c];
  #pragma unroll
  for (int k=0;k<4;k++){
    int ll = l + k - 3;
    if (ll >= 0) s += proj[(size_t)(b*SEQL + ll)*4096 + c] * cw[c*4+k];
  }
  uc[idx] = s * sigm(s);
}

// ---------------- chunked selective scan: pass 1 ----------------
__global__ __launch_bounds__(256) void scan_p1(
  const float* __restrict__ dl, const float* __restrict__ uc,
  const float* __restrict__ xp, const float* __restrict__ alog,
  float* __restrict__ locfin, float* __restrict__ Pst)
{
  int c = blockIdx.x*256 + threadIdx.x;
  int chunk = blockIdx.y, b = blockIdx.z;
  float a[SDIM];
  #pragma unroll
  for (int s=0;s<SDIM;s++) a[s] = -expf(alog[c*SDIM+s]);
  float st[SDIM] = {};
  float P[SDIM];
  #pragma unroll
  for (int s=0;s<SDIM;s++) P[s] = 1.f;
  size_t base = (size_t)b*SEQL + chunk*CLEN;
  #pragma unroll 2
  for (int l=0;l<CLEN;l++){
    size_t tix = base + l;
    float d = dl[tix*INNER + c];
    float u = uc[tix*INNER + c];
    const float* bc = xp + tix*96 + 64;
    float w = d*u;
    #pragma unroll
    for (int s=0;s<SDIM;s++){
      float p = __expf(d*a[s]);
      st[s] = p*st[s] + w*bc[s];
      P[s] *= p;
    }
  }
  size_t cb = (size_t)(b*NCH + chunk)*SDIM*INNER + c;
  #pragma unroll
  for (int s=0;s<SDIM;s++){
    locfin[cb + (size_t)s*INNER] = st[s];
    Pst[cb + (size_t)s*INNER] = P[s];
  }
}

// ---------------- pass 2 ----------------
__global__ __launch_bounds__(256) void scan_p2(
  const float* __restrict__ locfin, const float* __restrict__ Pst,
  float* __restrict__ initst)
{
  int c = blockIdx.x*256 + threadIdx.x;
  int s = blockIdx.y, b = blockIdx.z;
  float carry = 0.f;
  #pragma unroll 4
  for (int chunk=0; chunk<NCH; chunk++){
    size_t idx = ((size_t)(b*NCH + chunk)*SDIM + s)*INNER + c;
    initst[idx] = carry;
    carry = Pst[idx]*carry + locfin[idx];
  }
}

// ---------------- pass 3 ----------------
__global__ __launch_bounds__(256) void scan_p3(
  const float* __restrict__ dl, const float* __restrict__ uc,
  const float* __restrict__ xp, const float* __restrict__ alog,
  const float* __restrict__ dpar, const float* __restrict__ initst,
  float* __restrict__ y)
{
  int c = blockIdx.x*256 + threadIdx.x;
  int chunk = blockIdx.y, b = blockIdx.z;
  float a[SDIM], st[SDIM];
  #pragma unroll
  for (int s=0;s<SDIM;s++) a[s] = -expf(alog[c*SDIM+s]);
  size_t cb = (size_t)(b*NCH + chunk)*SDIM*INNER + c;
  #pragma unroll
  for (int s=0;s<SDIM;s++) st[s] = initst[cb + (size_t)s*INNER];
  float dv = dpar[c];
  size_t base = (size_t)b*SEQL + chunk*CLEN;
  #pragma unroll 2
  for (int l=0;l<CLEN;l++){
    size_t tix = base + l;
    float d = dl[tix*INNER + c];
    float u = uc[tix*INNER + c];
    const float* bc = xp + tix*96 + 64;
    float w = d*u, acc = 0.f;
    #pragma unroll
    for (int s=0;s<SDIM;s++){
      float p = __expf(d*a[s]);
      st[s] = p*st[s] + w*bc[s];
      acc += st[s]*bc[16+s];
    }
    y[tix*INNER + c] = acc + u*dv;
  }
}

// ---------------- y * silu(gate) ----------------
__global__ __launch_bounds__(256) void ygate_k(
  const float* __restrict__ y, const float* __restrict__ proj, float* __restrict__ yg)
{
  int idx = blockIdx.x*256 + threadIdx.x;
  int c = idx & (INNER-1); int t_ = idx >> 11;
  float g = proj[(size_t)t_*4096 + 2048 + c];
  yg[idx] = y[idx] * g * sigm(g);
}

// ---------------- rms1 + router (softmax top2) ----------------
__global__ __launch_bounds__(256) void rms_router_k(
  const float* __restrict__ x, const float* __restrict__ n1w,
  const float* __restrict__ rw, const float* __restrict__ rb,
  unsigned short* __restrict__ xnbf, int* __restrict__ ti, float* __restrict__ ts)
{
  __shared__ float sb[4];
  __shared__ float sb8[8][4];
  int tok = blockIdx.x, t = threadIdx.x;
  float4 v = *(const float4*)(x + (size_t)tok*HD + t*4);
  float tot = block_sum(v.x*v.x+v.y*v.y+v.z*v.z+v.w*v.w, sb);
  float rs = rsqrtf(tot/(float)HD + EPSV);
  float4 w = *(const float4*)(n1w + t*4);
  float4 xv; xv.x=v.x*rs*w.x; xv.y=v.y*rs*w.y; xv.z=v.z*rs*w.z; xv.w=v.w*rs*w.w;
  ushort4 o; o.x=f2bf(xv.x); o.y=f2bf(xv.y); o.z=f2bf(xv.z); o.w=f2bf(xv.w);
  *(ushort4*)(xnbf + (size_t)tok*HD + t*4) = o;
  float pe[8];
  #pragma unroll
  for (int e=0;e<8;e++){
    const float4 r4 = *(const float4*)(rw + (size_t)e*HD + t*4);
    pe[e] = xv.x*r4.x + xv.y*r4.y + xv.z*r4.z + xv.w*r4.w;
  }
  int lane = t & 63, wv = t >> 6;
  #pragma unroll
  for (int e=0;e<8;e++){
    float s = pe[e];
    #pragma unroll
    for (int m=32;m>=1;m>>=1) s += __shfl_xor(s, m, 64);
    if (lane==0) sb8[e][wv] = s;
  }
  __syncthreads();
  if (t==0){
    float lg[8], mx = -1e30f;
    for (int e=0;e<8;e++){ lg[e] = sb8[e][0]+sb8[e][1]+sb8[e][2]+sb8[e][3] + rb[e]; mx = fmaxf(mx, lg[e]); }
    float ex[8], sum=0.f;
    for (int e=0;e<8;e++){ ex[e]=expf(lg[e]-mx); sum+=ex[e]; }
    float inv = 1.f/sum;
    int i0=0; float p0=-1.f;
    for (int e=0;e<8;e++){ float p=ex[e]*inv; if (p>p0){p0=p;i0=e;} }
    int i1=-1; float p1=-1.f;
    for (int e=0;e<8;e++){ if (e==i0) continue; float p=ex[e]*inv; if (p>p1){p1=p;i1=e;} }
    ti[2*tok]=i0; ti[2*tok+1]=i1; ts[2*tok]=p0; ts[2*tok+1]=p1;
  }
}

// ---------------- routing ----------------
__global__ void route_build_k(const int* __restrict__ ti, const float* __restrict__ ts,
  int* __restrict__ slot_token, int* __restrict__ tok_slots, int* __restrict__ tile_expert)
{
  __shared__ int cnt[8], cur[8];
  int t = threadIdx.x;
  if (t < 8) cnt[t] = 0;
  __syncthreads();
  for (int tok = t; tok < NTOK; tok += 256){
    atomicAdd(&cnt[ti[2*tok]], 1);
    atomicAdd(&cnt[ti[2*tok+1]], 1);
  }
  __syncthreads();
  if (t == 0){
    int off = 0, tile = 0;
    for (int e=0;e<8;e++){
      cur[e] = off;
      int nt2 = (cnt[e] + 127) >> 7;
      for (int j=0;j<nt2;j++) tile_expert[tile++] = e;
      off += nt2 << 7;
    }
    while (tile < MAX_TILES) tile_expert[tile++] = -1;
  }
  __syncthreads();
  for (int i = t; i < SLOT_CAP; i += 256) slot_token[i] = -1;
  __syncthreads();
  for (int tok = t; tok < NTOK; tok += 256){
    #pragma unroll
    for (int j=0;j<2;j++){
      int e = ti[2*tok+j];
      int p = atomicAdd(&cur[e], 1);
      slot_token[p] = tok;
      tok_slots[2*tok+j] = p;
    }
  }
}

// ---------------- bf16 MFMA GEMM (fc1/fc2 path, B f32 converted on the fly) ----------------
template<bool GATHER, bool EXPERT>
__global__ __launch_bounds__(256) void gemm_bf16k(
  const unsigned short* __restrict__ A, int lda,
  const int* __restrict__ slot_token,
  const float* __restrict__ B0, long long expert_stride,
  const int* __restrict__ tile_expert,
  float* __restrict__ C, int ldc, int K)
{
  int mt = blockIdx.y, nt = blockIdx.x;
  const float* Bp = B0;
  if (EXPERT){
    int e = tile_expert[mt];
    if (e < 0) return;
    Bp = B0 + (long long)e * expert_stride;
  }
  int m0 = mt*128, n0 = nt*128;
  __shared__ unsigned short As[128][40];
  __shared__ unsigned short Bs[128][40];
  int t = threadIdx.x;
  int w = t >> 6, lane = t & 63;
  int wm = (w >> 1) * 64, wn = (w & 1) * 64;
  int lr = lane & 15, quad = lane >> 4;
  f32x4 acc[4][4] = {};

  int arow = t >> 1;
  int ahalf = t & 1;
  const unsigned short* asrc = nullptr;
  bool avalid = true;
  if (GATHER){
    int tok = slot_token[m0 + arow];
    avalid = (tok >= 0);
    if (avalid) asrc = A + (size_t)tok * lda;
  } else {
    asrc = A + (size_t)(m0 + arow) * lda;
  }
  const float* bsrc = Bp + (size_t)(n0 + arow) * K;

  for (int k0 = 0; k0 < K; k0 += 32){
    uint4 av0 = make_uint4(0,0,0,0), av1 = make_uint4(0,0,0,0);
    if (avalid){
      const uint4* p = (const uint4*)(asrc + k0 + ahalf*16);
      av0 = p[0]; av1 = p[1];
    }
    const float4* q = (const float4*)(bsrc + k0 + ahalf*16);
    float4 b0 = q[0], b1 = q[1], b2 = q[2], b3 = q[3];
    uint4 w0, w1;
    w0.x = (uint32_t)f2bf(b0.x) | ((uint32_t)f2bf(b0.y)<<16);
    w0.y = (uint32_t)f2bf(b0.z) | ((uint32_t)f2bf(b0.w)<<16);
    w0.z = (uint32_t)f2bf(b1.x) | ((uint32_t)f2bf(b1.y)<<16);
    w0.w = (uint32_t)f2bf(b1.z) | ((uint32_t)f2bf(b1.w)<<16);
    w1.x = (uint32_t)f2bf(b2.x) | ((uint32_t)f2bf(b2.y)<<16);
    w1.y = (uint32_t)f2bf(b2.z) | ((uint32_t)f2bf(b2.w)<<16);
    w1.z = (uint32_t)f2bf(b3.x) | ((uint32_t)f2bf(b3.y)<<16);
    w1.w = (uint32_t)f2bf(b3.z) | ((uint32_t)f2bf(b3.w)<<16);
    __syncthreads();
    *(uint4*)&As[arow][ahalf*16]     = av0;
    *(uint4*)&As[arow][ahalf*16 + 8] = av1;
    *(uint4*)&Bs[arow][ahalf*16]     = w0;
    *(uint4*)&Bs[arow][ahalf*16 + 8] = w1;
    __syncthreads();
    short8 af[4], bf[4];
    #pragma unroll
    for (int mi=0;mi<4;mi++) af[mi] = *(const short8*)&As[wm + mi*16 + lr][quad*8];
    #pragma unroll
    for (int ni=0;ni<4;ni++) bf[ni] = *(const short8*)&Bs[wn + ni*16 + lr][quad*8];
    #pragma unroll
    for (int mi=0;mi<4;mi++)
      #pragma unroll
      for (int ni=0;ni<4;ni++)
        acc[mi][ni] = __builtin_amdgcn_mfma_f32_16x16x32_bf16(af[mi], bf[ni], acc[mi][ni], 0, 0, 0);
  }
  #pragma unroll
  for (int mi=0;mi<4;mi++){
    int rbase = m0 + wm + mi*16 + quad*4;
    #pragma unroll
    for (int ni=0;ni<4;ni++){
      int col = n0 + wn + ni*16 + lr;
      float* cp = C + (size_t)rbase*ldc + col;
      #pragma unroll
      for (int r=0;r<4;r++) cp[(size_t)r*ldc] = acc[mi][ni][r];
    }
  }
}

// ---------------- f32 -> bf16 bulk convert (for emb) ----------------
__global__ __launch_bounds__(256) void f2bf_arr_k(
  const float* __restrict__ in, unsigned short* __restrict__ out)
{
  size_t i = (size_t)(blockIdx.x*256 + threadIdx.x) * 8;
  const float4* p = (const float4*)(in + i);
  float4 a = p[0], b = p[1];
  ushort4 o0, o1;
  o0.x=f2bf(a.x); o0.y=f2bf(a.y); o0.z=f2bf(a.z); o0.w=f2bf(a.w);
  o1.x=f2bf(b.x); o1.y=f2bf(b.y); o1.z=f2bf(b.z); o1.w=f2bf(b.w);
  *(ushort4*)(out + i)     = o0;
  *(ushort4*)(out + i + 4) = o1;
}

// ---------------- LM head: both-bf16 MFMA GEMM, global_load_lds staging ----------------
// C[2048,32000] = A(bf16)[2048,1024] * B(bf16)[32000,1024]^T
// Tile mapping: 16 consecutive tiles share one B panel (L2-hot per XCD via swizzle);
// A (4 MB bf16) becomes L2-resident per XCD.
__global__ __launch_bounds__(256) void lmhead_k(
  const unsigned short* __restrict__ A,
  const unsigned short* __restrict__ B,
  float* __restrict__ C)
{
  __shared__ __align__(16) unsigned short As[128][32];
  __shared__ __align__(16) unsigned short Bs[128][32];
  int orig = blockIdx.x;                 // 4000 blocks, 4000 % 8 == 0
  int swz = (orig & 7)*500 + (orig >> 3);
  int mt = swz & 15, nt = swz >> 4;      // mt in [0,16), nt in [0,250)
  int m0 = mt*128, n0 = nt*128;
  int t = threadIdx.x, w = t >> 6, lane = t & 63;
  int wm = (w >> 1) * 64, wn = (w & 1) * 64;
  int lr = lane & 15, quad = lane >> 4;

  // staging geometry: tile = 128 rows x 64 bytes = 8192 B; per issue 4 waves x 1024 B
  int o0 = w*1024 + lane*16;             // byte offset in tile, issue 0
  int o1 = o0 + 4096;                    // issue 1
  const unsigned short* gA0 = A + (size_t)(m0 + (o0>>6))*HD + ((o0&63)>>1);
  const unsigned short* gA1 = A + (size_t)(m0 + (o1>>6))*HD + ((o1&63)>>1);
  const unsigned short* gB0 = B + (size_t)(n0 + (o0>>6))*HD + ((o0&63)>>1);
  const unsigned short* gB1 = B + (size_t)(n0 + (o1>>6))*HD + ((o1&63)>>1);
  unsigned short* dA0 = &As[0][0] + (o0>>1);
  unsigned short* dA1 = &As[0][0] + (o1>>1);
  unsigned short* dB0 = &Bs[0][0] + (o0>>1);
  unsigned short* dB1 = &Bs[0][0] + (o1>>1);

  f32x4 acc[4][4] = {};
  for (int k0 = 0; k0 < HD; k0 += 32){
    __syncthreads();                     // prior iter's ds_reads done before overwrite
    gload16(gA0 + k0, dA0);
    gload16(gA1 + k0, dA1);
    gload16(gB0 + k0, dB0);
    gload16(gB1 + k0, dB1);
    __syncthreads();                     // compiler drains vmcnt(0) before barrier
    short8 af[4], bf[4];
    #pragma unroll
    for (int mi=0;mi<4;mi++) af[mi] = *(const short8*)&As[wm + mi*16 + lr][quad*8];
    #pragma unroll
    for (int ni=0;ni<4;ni++) bf[ni] = *(const short8*)&Bs[wn + ni*16 + lr][quad*8];
    #pragma unroll
    for (int mi=0;mi<4;mi++)
      #pragma unroll
      for (int ni=0;ni<4;ni++)
        acc[mi][ni] = __builtin_amdgcn_mfma_f32_16x16x32_bf16(af[mi], bf[ni], acc[mi][ni], 0, 0, 0);
  }
  #pragma unroll
  for (int mi=0;mi<4;mi++){
    int rbase = m0 + wm + mi*16 + quad*4;
    #pragma unroll
    for (int ni=0;ni<4;ni++){
      int col = n0 + wn + ni*16 + lr;
      float* cp = C + (size_t)rbase*VDIM + col;
      #pragma unroll
      for (int r=0;r<4;r++) cp[(size_t)r*VDIM] = acc[mi][ni][r];
    }
  }
}

// ---------------- silu(h1a)*h1b -> hidden bf16 ----------------
__global__ __launch_bounds__(256) void silu_mul_k(
  const float* __restrict__ h1, unsigned short* __restrict__ hidden)
{
  int idx = blockIdx.x*256 + threadIdx.x;   // over SLOT_CAP*FFN
  int f = idx & (FFN-1); int slot = idx >> 11;
  float a = h1[(size_t)slot*2*FFN + f];
  float b = h1[(size_t)slot*2*FFN + FFN + f];
  hidden[idx] = f2bf(a*sigm(a)*b);
}

// ---------------- combine experts + final rms -> xnf bf16 ----------------
__global__ __launch_bounds__(256) void combine_rms_k(
  const float* __restrict__ x, const float* __restrict__ eo,
  const int* __restrict__ tok_slots, const float* __restrict__ ts,
  const float* __restrict__ fw, unsigned short* __restrict__ xnf)
{
  __shared__ float sb[4];
  int tok = blockIdx.x, t = threadIdx.x;
  int p0 = tok_slots[2*tok], p1 = tok_slots[2*tok+1];
  float s0 = ts[2*tok], s1 = ts[2*tok+1];
  float4 v  = *(const float4*)(x  + (size_t)tok*HD + t*4);
  float4 e0 = *(const float4*)(eo + (size_t)p0*HD + t*4);
  float4 e1 = *(const float4*)(eo + (size_t)p1*HD + t*4);
  v.x += s0*e0.x + s1*e1.x;
  v.y += s0*e0.y + s1*e1.y;
  v.z += s0*e0.z + s1*e1.z;
  v.w += s0*e0.w + s1*e1.w;
  float tot = block_sum(v.x*v.x+v.y*v.y+v.z*v.z+v.w*v.w, sb);
  float rs = rsqrtf(tot/(float)HD + EPSV);
  float4 w = *(const float4*)(fw + t*4);
  ushort4 o;
  o.x=f2bf(v.x*rs*w.x); o.y=f2bf(v.y*rs*w.y); o.z=f2bf(v.z*rs*w.z); o.w=f2bf(v.w*rs*w.w);
  *(ushort4*)(xnf + (size_t)tok*HD + t*4) = o;
}

extern "C" void kernel_launch(void* const* d_in, const int* in_sizes, int n_in,
                              void* d_out, int out_size, void* d_ws, size_t ws_size,
                              hipStream_t stream)
{
  const int*   ids  = (const int*)  d_in[0];
  const float* emb  = (const float*)d_in[1];
  const float* n0w  = (const float*)d_in[2];
  const float* ipw  = (const float*)d_in[3];
  const float* cw   = (const float*)d_in[4];
  const float* cb   = (const float*)d_in[5];
  const float* xpw  = (const float*)d_in[6];
  const float* dtw  = (const float*)d_in[7];
  const float* dtb  = (const float*)d_in[8];
  const float* alog = (const float*)d_in[9];
  const float* dpar = (const float*)d_in[10];
  const float* opw  = (const float*)d_in[11];
  const float* n1w  = (const float*)d_in[12];
  const float* rw   = (const float*)d_in[13];
  const float* rb   = (const float*)d_in[14];
  const float* f1w  = (const float*)d_in[15];
  const float* f2w  = (const float*)d_in[16];
  const float* fnw  = (const float*)d_in[17];
  float* out = (float*)d_out;
  char* ws = (char*)d_ws;

  // workspace layout (bytes); h1 overlays the dead proj..y span
  size_t o_x       = 0;                          // 8,388,608
  size_t o_xnbf    = o_x + 8388608;              // 4,194,304
  size_t o_ti      = o_xnbf + 4194304;           // 16,384
  size_t o_ts      = o_ti + 16384;               // 16,384
  size_t o_slott   = o_ts + 16384;               // 20,480
  size_t o_tslots  = o_slott + 20480;            // 16,384
  size_t o_tile    = o_tslots + 16384;           // 256
  size_t o_xn      = o_tile + 256;               // 8,388,608
  size_t o_proj    = o_xn + 8388608;             // 33,554,432
  size_t o_uconv   = o_proj + 33554432;          // 16,777,216
  size_t o_xp      = o_uconv + 16777216;         // 786,432
  size_t o_dl      = o_xp + 786432;              // 16,777,216
  size_t o_y       = o_dl + 16777216;            // 16,777,216
  size_t o_yg      = o_y + 16777216;             // 16,777,216
  size_t o_h1      = o_proj;                     // 83,886,080 (overlay, fits in proj..y span)
  size_t o_hidden  = o_yg + 16777216;            // 20,971,520
  size_t o_eo      = o_hidden + 20971520;        // 20,971,520
  size_t o_xnf     = o_eo + 20971520;            // 4,194,304
  // scan carry buffers overlay hidden/eo (dead until after scan): 3 x 8 MB
  size_t o_locfin  = o_hidden;                   // 8,388,608
  size_t o_pst     = o_locfin + 8388608;         // 8,388,608
  size_t o_init    = o_pst + 8388608;            // 8,388,608
  // bf16 emb (65,536,000 B) overlays proj..dl span — dead after silu_mul (h1 is its
  // last reader); live from post-silu_mul conversion until lmhead at the end.
  size_t o_embbf   = o_proj;

  float* x      = (float*)(ws + o_x);
  unsigned short* xnbf = (unsigned short*)(ws + o_xnbf);
  int*   ti     = (int*)(ws + o_ti);
  float* ts     = (float*)(ws + o_ts);
  int*   slott  = (int*)(ws + o_slott);
  int*   tslots = (int*)(ws + o_tslots);
  int*   tile_e = (int*)(ws + o_tile);
  float* xn     = (float*)(ws + o_xn);
  float* proj   = (float*)(ws + o_proj);
  float* uconv  = (float*)(ws + o_uconv);
  float* xp     = (float*)(ws + o_xp);
  float* dl     = (float*)(ws + o_dl);
  float* y      = (float*)(ws + o_y);
  float* yg     = (float*)(ws + o_yg);
  float* h1     = (float*)(ws + o_h1);
  unsigned short* hidden = (unsigned short*)(ws + o_hidden);
  float* eo     = (float*)(ws + o_eo);
  unsigned short* xnf = (unsigned short*)(ws + o_xnf);
  float* locfin = (float*)(ws + o_locfin);
  float* pst    = (float*)(ws + o_pst);
  float* initst = (float*)(ws + o_init);
  unsigned short* embbf = (unsigned short*)(ws + o_embbf);

  embed_rms_k<<<NTOK,256,0,stream>>>(ids, emb, n0w, x, xn);
  // in_proj: [2048,1024] x [4096,1024]^T -> proj [2048,4096]
  gemm_f32k<0><<<dim3(64,32),256,0,stream>>>(xn, HD, ipw, proj, 4096, 4096, HD, nullptr);
  conv_silu_k<<<(NTOK*INNER)/256,256,0,stream>>>(proj, cw, cb, uconv);
  // x_proj: [2048,2048] x [96,2048]^T -> xp [2048,96]
  gemm_f32k<0><<<dim3(2,32),256,0,stream>>>(uconv, INNER, xpw, xp, 96, 96, INNER, nullptr);
  // dt_proj + bias + softplus
  gemm_f32k<1><<<dim3(32,32),256,0,stream>>>(xp, 96, dtw, dl, INNER, INNER, DTR, dtb);
  scan_p1<<<dim3(8,NCH,2),256,0,stream>>>(dl, uconv, xp, alog, locfin, pst);
  scan_p2<<<dim3(8,SDIM,2),256,0,stream>>>(locfin, pst, initst);
  scan_p3<<<dim3(8,NCH,2),256,0,stream>>>(dl, uconv, xp, alog, dpar, initst, y);
  ygate_k<<<(NTOK*INNER)/256,256,0,stream>>>(y, proj, yg);
  // out_proj + residual
  gemm_f32k<2><<<dim3(16,32),256,0,stream>>>(yg, INNER, opw, x, HD, HD, INNER, nullptr);
  rms_router_k<<<NTOK,256,0,stream>>>(x, n1w, rw, rb, xnbf, ti, ts);
  route_build_k<<<1,256,0,stream>>>(ti, ts, slott, tslots, tile_e);
  // fc1: gathered xn (bf16) x fc1_w[e] -> h1 [5120,4096]
  gemm_bf16k<true,true><<<dim3(32,MAX_TILES),256,0,stream>>>(
      xnbf, HD, slott, f1w, 4096LL*1024LL, tile_e, h1, 4096, HD);
  silu_mul_k<<<(SLOT_CAP*FFN)/256,256,0,stream>>>(h1, hidden);
  // h1/proj span now dead -> convert emb to bf16 there for the LM head
  f2bf_arr_k<<<(VDIM*HD/8)/256,256,0,stream>>>(emb, embbf);
  // fc2: hidden (bf16) x fc2_w[e] -> eo [5120,1024]
  gemm_bf16k<false,true><<<dim3(8,MAX_TILES),256,0,stream>>>(
      hidden, FFN, nullptr, f2w, 1024LL*2048LL, tile_e, eo, HD, FFN);
  combine_rms_k<<<NTOK,256,0,stream>>>(x, eo, tslots, ts, fnw, xnf);
  // LM head: xnf (bf16) x embbf (bf16) -> out [2048,32000]
  lmhead_k<<<4000,256,0,stream>>>(xnf, embbf, out);
}

// Round 2
// 1427.541 us; speedup vs baseline: 1.0746x; 1.0637x over previous
//
#include <hip/hip_runtime.h>
#include <cstdint>

#define HD 1024
#define INNER 2048
#define NTOK 2048
#define SEQL 1024
#define SDIM 16
#define DTR 64
#define VDIM 32000
#define FFN 2048
#define EPSV 1e-5f
#define SLOT_CAP 5120
#define MAX_TILES 40
#define NCH 32
#define CLEN 32

typedef __attribute__((ext_vector_type(8))) short short8;
typedef __attribute__((ext_vector_type(4))) float f32x4;

__device__ __forceinline__ unsigned short f2bf(float f){
  unsigned int u = __float_as_uint(f);
  u += 0x7FFF + ((u >> 16) & 1);
  return (unsigned short)(u >> 16);
}
__device__ __forceinline__ float sigm(float x){ return 1.f/(1.f+__expf(-x)); }

__device__ __forceinline__ void gload16(const unsigned short* g, unsigned short* l){
  __builtin_amdgcn_global_load_lds(
    (const __attribute__((address_space(1))) unsigned int*)g,
    (__attribute__((address_space(3))) unsigned int*)l, 16, 0, 0);
}

__device__ __forceinline__ float block_sum(float v, float* sb){
  #pragma unroll
  for (int m=32;m>=1;m>>=1) v += __shfl_xor(v, m, 64);
  int lane = threadIdx.x & 63, w = threadIdx.x >> 6;
  if (lane==0) sb[w]=v;
  __syncthreads();
  float s = sb[0]+sb[1]+sb[2]+sb[3];
  __syncthreads();
  return s;
}

// ---------------- embed + rms0 ----------------
__global__ __launch_bounds__(256) void embed_rms_k(
  const int* __restrict__ ids, const float* __restrict__ emb,
  const float* __restrict__ n0w, float* __restrict__ x, float* __restrict__ xn)
{
  __shared__ float sb[4];
  int tok = blockIdx.x, t = threadIdx.x;
  int id = ids[tok];
  float4 v = *(const float4*)(emb + (size_t)id*HD + t*4);
  *(float4*)(x + (size_t)tok*HD + t*4) = v;
  float tot = block_sum(v.x*v.x+v.y*v.y+v.z*v.z+v.w*v.w, sb);
  float rs = rsqrtf(tot/(float)HD + EPSV);
  float4 w = *(const float4*)(n0w + t*4);
  float4 o; o.x=v.x*rs*w.x; o.y=v.y*rs*w.y; o.z=v.z*rs*w.z; o.w=v.w*rs*w.w;
  *(float4*)(xn + (size_t)tok*HD + t*4) = o;
}

// ---------------- generic fp32 GEMM: C[M,N] = A[M,K(lda)] * B[N,K]^T ----------------
template<int EPI>
__global__ __launch_bounds__(256) void gemm_f32k(
  const float* __restrict__ A, int lda,
  const float* __restrict__ B,
  float* __restrict__ C, int ldc,
  int N, int K, const float* __restrict__ bias)
{
  __shared__ float As[16][68];
  __shared__ float Bs[16][68];
  int m0 = blockIdx.y*64, n0 = blockIdx.x*64;
  int t = threadIdx.x, tm = t & 15, tn = t >> 4;
  float acc[4][4] = {};
  int srow = t >> 2, skq = (t & 3) * 4;
  const float* arow = A + (size_t)(m0 + srow)*lda + skq;
  int nrow = n0 + srow;
  const float* brow = B + (size_t)nrow*K + skq;
  bool bok = nrow < N;
  for (int k0 = 0; k0 < K; k0 += 16) {
    float4 a = *(const float4*)(arow + k0);
    float4 b = bok ? *(const float4*)(brow + k0) : make_float4(0.f,0.f,0.f,0.f);
    __syncthreads();
    As[skq+0][srow]=a.x; As[skq+1][srow]=a.y; As[skq+2][srow]=a.z; As[skq+3][srow]=a.w;
    Bs[skq+0][srow]=b.x; Bs[skq+1][srow]=b.y; Bs[skq+2][srow]=b.z; Bs[skq+3][srow]=b.w;
    __syncthreads();
    #pragma unroll
    for (int k=0;k<16;k++){
      const float4 av = *(const float4*)&As[k][tm*4];
      const float4 bv = *(const float4*)&Bs[k][tn*4];
      float am[4] = {av.x, av.y, av.z, av.w};
      float bn[4] = {bv.x, bv.y, bv.z, bv.w};
      #pragma unroll
      for (int i=0;i<4;i++)
        #pragma unroll
        for (int j=0;j<4;j++)
          acc[i][j] += am[i]*bn[j];
    }
  }
  #pragma unroll
  for (int i=0;i<4;i++){
    int row = m0 + tm*4 + i;
    #pragma unroll
    for (int j=0;j<4;j++){
      int col = n0 + tn*4 + j;
      if (col < N){
        float v = acc[i][j];
        if (EPI==1){ v += bias[col]; v = (v > 20.f) ? v : log1pf(expf(v)); }
        if (EPI==2){ v += C[(size_t)row*ldc + col]; }
        C[(size_t)row*ldc + col] = v;
      }
    }
  }
}

// ---------------- causal depthwise conv (K=4) + silu ----------------
__global__ __launch_bounds__(256) void conv_silu_k(
  const float* __restrict__ proj, const float* __restrict__ cw,
  const float* __restrict__ cb, float* __restrict__ uc)
{
  int idx = blockIdx.x*256 + threadIdx.x;     // over B*L*INNER
  int c = idx & (INNER-1);
  int l = (idx >> 11) & (SEQL-1);
  int b = idx >> 21;
  float s = cb[c];
  #pragma unroll
  for (int k=0;k<4;k++){
    int ll = l + k - 3;
    if (ll >= 0) s += proj[(size_t)(b*SEQL + ll)*4096 + c] * cw[c*4+k];
  }
  uc[idx] = s * sigm(s);
}

// ---------------- chunked selective scan: pass 1 ----------------
__global__ __launch_bounds__(256) void scan_p1(
  const float* __restrict__ dl, const float* __restrict__ uc,
  const float* __restrict__ xp, const float* __restrict__ alog,
  float* __restrict__ locfin, float* __restrict__ Pst)
{
  int c = blockIdx.x*256 + threadIdx.x;
  int chunk = blockIdx.y, b = blockIdx.z;
  float a[SDIM];
  #pragma unroll
  for (int s=0;s<SDIM;s++) a[s] = -expf(alog[c*SDIM+s]);
  float st[SDIM] = {};
  float P[SDIM];
  #pragma unroll
  for (int s=0;s<SDIM;s++) P[s] = 1.f;
  size_t base = (size_t)b*SEQL + chunk*CLEN;
  #pragma unroll 2
  for (int l=0;l<CLEN;l++){
    size_t tix = base + l;
    float d = dl[tix*INNER + c];
    float u = uc[tix*INNER + c];
    const float* bc = xp + tix*96 + 64;
    float w = d*u;
    #pragma unroll
    for (int s=0;s<SDIM;s++){
      float p = __expf(d*a[s]);
      st[s] = p*st[s] + w*bc[s];
      P[s] *= p;
    }
  }
  size_t cb = (size_t)(b*NCH + chunk)*SDIM*INNER + c;
  #pragma unroll
  for (int s=0;s<SDIM;s++){
    locfin[cb + (size_t)s*INNER] = st[s];
    Pst[cb + (size_t)s*INNER] = P[s];
  }
}

// ---------------- pass 2 ----------------
__global__ __launch_bounds__(256) void scan_p2(
  const float* __restrict__ locfin, const float* __restrict__ Pst,
  float* __restrict__ initst)
{
  int c = blockIdx.x*256 + threadIdx.x;
  int s = blockIdx.y, b = blockIdx.z;
  float carry = 0.f;
  #pragma unroll 4
  for (int chunk=0; chunk<NCH; chunk++){
    size_t idx = ((size_t)(b*NCH + chunk)*SDIM + s)*INNER + c;
    initst[idx] = carry;
    carry = Pst[idx]*carry + locfin[idx];
  }
}

// ---------------- pass 3 ----------------
__global__ __launch_bounds__(256) void scan_p3(
  const float* __restrict__ dl, const float* __restrict__ uc,
  const float* __restrict__ xp, const float* __restrict__ alog,
  const float* __restrict__ dpar, const float* __restrict__ initst,
  float* __restrict__ y)
{
  int c = blockIdx.x*256 + threadIdx.x;
  int chunk = blockIdx.y, b = blockIdx.z;
  float a[SDIM], st[SDIM];
  #pragma unroll
  for (int s=0;s<SDIM;s++) a[s] = -expf(alog[c*SDIM+s]);
  size_t cb = (size_t)(b*NCH + chunk)*SDIM*INNER + c;
  #pragma unroll
  for (int s=0;s<SDIM;s++) st[s] = initst[cb + (size_t)s*INNER];
  float dv = dpar[c];
  size_t base = (size_t)b*SEQL + chunk*CLEN;
  #pragma unroll 2
  for (int l=0;l<CLEN;l++){
    size_t tix = base + l;
    float d = dl[tix*INNER + c];
    float u = uc[tix*INNER + c];
    const float* bc = xp + tix*96 + 64;
    float w = d*u, acc = 0.f;
    #pragma unroll
    for (int s=0;s<SDIM;s++){
      float p = __expf(d*a[s]);
      st[s] = p*st[s] + w*bc[s];
      acc += st[s]*bc[16+s];
    }
    y[tix*INNER + c] = acc + u*dv;
  }
}

// ---------------- y * silu(gate) ----------------
__global__ __launch_bounds__(256) void ygate_k(
  const float* __restrict__ y, const float* __restrict__ proj, float* __restrict__ yg)
{
  int idx = blockIdx.x*256 + threadIdx.x;
  int c = idx & (INNER-1); int t_ = idx >> 11;
  float g = proj[(size_t)t_*4096 + 2048 + c];
  yg[idx] = y[idx] * g * sigm(g);
}

// ---------------- rms1 + router (softmax top2) ----------------
__global__ __launch_bounds__(256) void rms_router_k(
  const float* __restrict__ x, const float* __restrict__ n1w,
  const float* __restrict__ rw, const float* __restrict__ rb,
  unsigned short* __restrict__ xnbf, int* __restrict__ ti, float* __restrict__ ts)
{
  __shared__ float sb[4];
  __shared__ float sb8[8][4];
  int tok = blockIdx.x, t = threadIdx.x;
  float4 v = *(const float4*)(x + (size_t)tok*HD + t*4);
  float tot = block_sum(v.x*v.x+v.y*v.y+v.z*v.z+v.w*v.w, sb);
  float rs = rsqrtf(tot/(float)HD + EPSV);
  float4 w = *(const float4*)(n1w + t*4);
  float4 xv; xv.x=v.x*rs*w.x; xv.y=v.y*rs*w.y; xv.z=v.z*rs*w.z; xv.w=v.w*rs*w.w;
  ushort4 o; o.x=f2bf(xv.x); o.y=f2bf(xv.y); o.z=f2bf(xv.z); o.w=f2bf(xv.w);
  *(ushort4*)(xnbf + (size_t)tok*HD + t*4) = o;
  float pe[8];
  #pragma unroll
  for (int e=0;e<8;e++){
    const float4 r4 = *(const float4*)(rw + (size_t)e*HD + t*4);
    pe[e] = xv.x*r4.x + xv.y*r4.y + xv.z*r4.z + xv.w*r4.w;
  }
  int lane = t & 63, wv = t >> 6;
  #pragma unroll
  for (int e=0;e<8;e++){
    float s = pe[e];
    #pragma unroll
    for (int m=32;m>=1;m>>=1) s += __shfl_xor(s, m, 64);
    if (lane==0) sb8[e][wv] = s;
  }
  __syncthreads();
  if (t==0){
    float lg[8], mx = -1e30f;
    for (int e=0;e<8;e++){ lg[e] = sb8[e][0]+sb8[e][1]+sb8[e][2]+sb8[e][3] + rb[e]; mx = fmaxf(mx, lg[e]); }
    float ex[8], sum=0.f;
    for (int e=0;e<8;e++){ ex[e]=expf(lg[e]-mx); sum+=ex[e]; }
    float inv = 1.f/sum;
    int i0=0; float p0=-1.f;
    for (int e=0;e<8;e++){ float p=ex[e]*inv; if (p>p0){p0=p;i0=e;} }
    int i1=-1; float p1=-1.f;
    for (int e=0;e<8;e++){ if (e==i0) continue; float p=ex[e]*inv; if (p>p1){p1=p;i1=e;} }
    ti[2*tok]=i0; ti[2*tok+1]=i1; ts[2*tok]=p0; ts[2*tok+1]=p1;
  }
}

// ---------------- routing ----------------
__global__ void route_build_k(const int* __restrict__ ti, const float* __restrict__ ts,
  int* __restrict__ slot_token, int* __restrict__ tok_slots, int* __restrict__ tile_expert)
{
  __shared__ int cnt[8], cur[8];
  int t = threadIdx.x;
  if (t < 8) cnt[t] = 0;
  __syncthreads();
  for (int tok = t; tok < NTOK; tok += 256){
    atomicAdd(&cnt[ti[2*tok]], 1);
    atomicAdd(&cnt[ti[2*tok+1]], 1);
  }
  __syncthreads();
  if (t == 0){
    int off = 0, tile = 0;
    for (int e=0;e<8;e++){
      cur[e] = off;
      int nt2 = (cnt[e] + 127) >> 7;
      for (int j=0;j<nt2;j++) tile_expert[tile++] = e;
      off += nt2 << 7;
    }
    while (tile < MAX_TILES) tile_expert[tile++] = -1;
  }
  __syncthreads();
  for (int i = t; i < SLOT_CAP; i += 256) slot_token[i] = -1;
  __syncthreads();
  for (int tok = t; tok < NTOK; tok += 256){
    #pragma unroll
    for (int j=0;j<2;j++){
      int e = ti[2*tok+j];
      int p = atomicAdd(&cur[e], 1);
      slot_token[p] = tok;
      tok_slots[2*tok+j] = p;
    }
  }
}

// ---------------- bf16 MFMA GEMM (fc1/fc2 path, B f32 converted on the fly) ----------------
template<bool GATHER, bool EXPERT>
__global__ __launch_bounds__(256) void gemm_bf16k(
  const unsigned short* __restrict__ A, int lda,
  const int* __restrict__ slot_token,
  const float* __restrict__ B0, long long expert_stride,
  const int* __restrict__ tile_expert,
  float* __restrict__ C, int ldc, int K)
{
  int mt = blockIdx.y, nt = blockIdx.x;
  const float* Bp = B0;
  if (EXPERT){
    int e = tile_expert[mt];
    if (e < 0) return;
    Bp = B0 + (long long)e * expert_stride;
  }
  int m0 = mt*128, n0 = nt*128;
  __shared__ unsigned short As[128][40];
  __shared__ unsigned short Bs[128][40];
  int t = threadIdx.x;
  int w = t >> 6, lane = t & 63;
  int wm = (w >> 1) * 64, wn = (w & 1) * 64;
  int lr = lane & 15, quad = lane >> 4;
  f32x4 acc[4][4] = {};

  int arow = t >> 1;
  int ahalf = t & 1;
  const unsigned short* asrc = nullptr;
  bool avalid = true;
  if (GATHER){
    int tok = slot_token[m0 + arow];
    avalid = (tok >= 0);
    if (avalid) asrc = A + (size_t)tok * lda;
  } else {
    asrc = A + (size_t)(m0 + arow) * lda;
  }
  const float* bsrc = Bp + (size_t)(n0 + arow) * K;

  for (int k0 = 0; k0 < K; k0 += 32){
    uint4 av0 = make_uint4(0,0,0,0), av1 = make_uint4(0,0,0,0);
    if (avalid){
      const uint4* p = (const uint4*)(asrc + k0 + ahalf*16);
      av0 = p[0]; av1 = p[1];
    }
    const float4* q = (const float4*)(bsrc + k0 + ahalf*16);
    float4 b0 = q[0], b1 = q[1], b2 = q[2], b3 = q[3];
    uint4 w0, w1;
    w0.x = (uint32_t)f2bf(b0.x) | ((uint32_t)f2bf(b0.y)<<16);
    w0.y = (uint32_t)f2bf(b0.z) | ((uint32_t)f2bf(b0.w)<<16);
    w0.z = (uint32_t)f2bf(b1.x) | ((uint32_t)f2bf(b1.y)<<16);
    w0.w = (uint32_t)f2bf(b1.z) | ((uint32_t)f2bf(b1.w)<<16);
    w1.x = (uint32_t)f2bf(b2.x) | ((uint32_t)f2bf(b2.y)<<16);
    w1.y = (uint32_t)f2bf(b2.z) | ((uint32_t)f2bf(b2.w)<<16);
    w1.z = (uint32_t)f2bf(b3.x) | ((uint32_t)f2bf(b3.y)<<16);
    w1.w = (uint32_t)f2bf(b3.z) | ((uint32_t)f2bf(b3.w)<<16);
    __syncthreads();
    *(uint4*)&As[arow][ahalf*16]     = av0;
    *(uint4*)&As[arow][ahalf*16 + 8] = av1;
    *(uint4*)&Bs[arow][ahalf*16]     = w0;
    *(uint4*)&Bs[arow][ahalf*16 + 8] = w1;
    __syncthreads();
    short8 af[4], bf[4];
    #pragma unroll
    for (int mi=0;mi<4;mi++) af[mi] = *(const short8*)&As[wm + mi*16 + lr][quad*8];
    #pragma unroll
    for (int ni=0;ni<4;ni++) bf[ni] = *(const short8*)&Bs[wn + ni*16 + lr][quad*8];
    #pragma unroll
    for (int mi=0;mi<4;mi++)
      #pragma unroll
      for (int ni=0;ni<4;ni++)
        acc[mi][ni] = __builtin_amdgcn_mfma_f32_16x16x32_bf16(af[mi], bf[ni], acc[mi][ni], 0, 0, 0);
  }
  #pragma unroll
  for (int mi=0;mi<4;mi++){
    int rbase = m0 + wm + mi*16 + quad*4;
    #pragma unroll
    for (int ni=0;ni<4;ni++){
      int col = n0 + wn + ni*16 + lr;
      float* cp = C + (size_t)rbase*ldc + col;
      #pragma unroll
      for (int r=0;r<4;r++) cp[(size_t)r*ldc] = acc[mi][ni][r];
    }
  }
}

// ---------------- f32 -> bf16 bulk convert (for emb) ----------------
__global__ __launch_bounds__(256) void f2bf_arr_k(
  const float* __restrict__ in, unsigned short* __restrict__ out)
{
  size_t i = (size_t)(blockIdx.x*256 + threadIdx.x) * 8;
  const float4* p = (const float4*)(in + i);
  float4 a = p[0], b = p[1];
  ushort4 o0, o1;
  o0.x=f2bf(a.x); o0.y=f2bf(a.y); o0.z=f2bf(a.z); o0.w=f2bf(a.w);
  o1.x=f2bf(b.x); o1.y=f2bf(b.y); o1.z=f2bf(b.z); o1.w=f2bf(b.w);
  *(ushort4*)(out + i)     = o0;
  *(ushort4*)(out + i + 4) = o1;
}

// ---------------- LM head: both-bf16 MFMA GEMM, dbuf global_load_lds + slot-XOR swizzle ----
// C[2048,32000] = A(bf16)[2048,1024] * B(bf16)[32000,1024]^T
// T3-minimum 2-phase: stage tile t+1 into the other buffer BEFORE computing tile t;
// ONE __syncthreads per tile (its vmcnt(0) drain lands after a full compute phase).
// Slot-XOR swizzle (both-sides, rule 21): phys slot = slot ^ ((row>>1)&3) applied via
// pre-swizzled per-lane global k-offset (LDS dest stays linear for global_load_lds)
// and the matching XOR on the ds_read fragment address -> 2-way min aliasing (free).
__global__ __launch_bounds__(256) void lmhead_k(
  const unsigned short* __restrict__ A,
  const unsigned short* __restrict__ B,
  float* __restrict__ C)
{
  __shared__ __align__(16) unsigned short As0[128][32];
  __shared__ __align__(16) unsigned short Bs0[128][32];
  __shared__ __align__(16) unsigned short As1[128][32];
  __shared__ __align__(16) unsigned short Bs1[128][32];
  int orig = blockIdx.x;                 // 4000 blocks, 4000 % 8 == 0
  int swz = (orig & 7)*500 + (orig >> 3);
  int mt = swz & 15, nt = swz >> 4;      // mt in [0,16), nt in [0,250)
  int m0 = mt*128, n0 = nt*128;
  int t = threadIdx.x, w = t >> 6, lane = t & 63;
  int wm = (w >> 1) * 64, wn = (w & 1) * 64;
  int lr = lane & 15, quad = lane >> 4;

  // staging: tile = 128 rows x 64 B; 4 lanes cover one row's 64 B (slot-permuted)
  int row0 = w*16 + (lane>>2);
  int koff = ((lane&3) ^ ((lane>>3)&3)) * 8;   // swizzled 16B k-chunk within row
  int p0 = (w*1024 + lane*16) >> 1;            // ushort offset in tile, issue 0
  int p1 = p0 + 2048;                          // issue 1 (+4096 B = rows +64)
  const unsigned short* gA0 = A + (size_t)(m0 + row0)*HD + koff;
  const unsigned short* gA1 = gA0 + (size_t)64*HD;
  const unsigned short* gB0 = B + (size_t)(n0 + row0)*HD + koff;
  const unsigned short* gB1 = gB0 + (size_t)64*HD;

  int sq = (quad ^ ((lr>>1)&3)) * 8;           // swizzled slot for fragment reads

  f32x4 acc[4][4] = {};

#define STAGE(AS,BS,k0) \
    gload16(gA0 + (k0), &AS[0][0] + p0); \
    gload16(gA1 + (k0), &AS[0][0] + p1); \
    gload16(gB0 + (k0), &BS[0][0] + p0); \
    gload16(gB1 + (k0), &BS[0][0] + p1);

#define COMPUTE(AS,BS) { \
    short8 af[4], bf[4]; \
    _Pragma("unroll") \
    for (int mi=0;mi<4;mi++) af[mi] = *(const short8*)&AS[wm + mi*16 + lr][sq]; \
    _Pragma("unroll") \
    for (int ni=0;ni<4;ni++) bf[ni] = *(const short8*)&BS[wn + ni*16 + lr][sq]; \
    _Pragma("unroll") \
    for (int mi=0;mi<4;mi++) \
      _Pragma("unroll") \
      for (int ni=0;ni<4;ni++) \
        acc[mi][ni] = __builtin_amdgcn_mfma_f32_16x16x32_bf16(af[mi], bf[ni], acc[mi][ni], 0, 0, 0); }

  STAGE(As0,Bs0, 0);
  __syncthreads();                        // drains vmcnt(0): buf0 ready
  for (int k0 = 0; k0 < HD; k0 += 64){
    STAGE(As1,Bs1, k0+32);                // prefetch next tile into buf1
    COMPUTE(As0,Bs0);                     // compute current from buf0
    __syncthreads();                      // drain: buf1 ready; reads of buf0 done
    if (k0 + 64 < HD) { STAGE(As0,Bs0, k0+64); }
    COMPUTE(As1,Bs1);
    __syncthreads();
  }
#undef STAGE
#undef COMPUTE

  #pragma unroll
  for (int mi=0;mi<4;mi++){
    int rbase = m0 + wm + mi*16 + quad*4;
    #pragma unroll
    for (int ni=0;ni<4;ni++){
      int col = n0 + wn + ni*16 + lr;
      float* cp = C + (size_t)rbase*VDIM + col;
      #pragma unroll
      for (int r=0;r<4;r++) cp[(size_t)r*VDIM] = acc[mi][ni][r];
    }
  }
}

// ---------------- silu(h1a)*h1b -> hidden bf16 ----------------
__global__ __launch_bounds__(256) void silu_mul_k(
  const float* __restrict__ h1, unsigned short* __restrict__ hidden)
{
  int idx = blockIdx.x*256 + threadIdx.x;   // over SLOT_CAP*FFN
  int f = idx & (FFN-1); int slot = idx >> 11;
  float a = h1[(size_t)slot*2*FFN + f];
  float b = h1[(size_t)slot*2*FFN + FFN + f];
  hidden[idx] = f2bf(a*sigm(a)*b);
}

// ---------------- combine experts + final rms -> xnf bf16 ----------------
__global__ __launch_bounds__(256) void combine_rms_k(
  const float* __restrict__ x, const float* __restrict__ eo,
  const int* __restrict__ tok_slots, const float* __restrict__ ts,
  const float* __restrict__ fw, unsigned short* __restrict__ xnf)
{
  __shared__ float sb[4];
  int tok = blockIdx.x, t = threadIdx.x;
  int p0 = tok_slots[2*tok], p1 = tok_slots[2*tok+1];
  float s0 = ts[2*tok], s1 = ts[2*tok+1];
  float4 v  = *(const float4*)(x  + (size_t)tok*HD + t*4);
  float4 e0 = *(const float4*)(eo + (size_t)p0*HD + t*4);
  float4 e1 = *(const float4*)(eo + (size_t)p1*HD + t*4);
  v.x += s0*e0.x + s1*e1.x;
  v.y += s0*e0.y + s1*e1.y;
  v.z += s0*e0.z + s1*e1.z;
  v.w += s0*e0.w + s1*e1.w;
  float tot = block_sum(v.x*v.x+v.y*v.y+v.z*v.z+v.w*v.w, sb);
  float rs = rsqrtf(tot/(float)HD + EPSV);
  float4 w = *(const float4*)(fw + t*4);
  ushort4 o;
  o.x=f2bf(v.x*rs*w.x); o.y=f2bf(v.y*rs*w.y); o.z=f2bf(v.z*rs*w.z); o.w=f2bf(v.w*rs*w.w);
  *(ushort4*)(xnf + (size_t)tok*HD + t*4) = o;
}

extern "C" void kernel_launch(void* const* d_in, const int* in_sizes, int n_in,
                              void* d_out, int out_size, void* d_ws, size_t ws_size,
                              hipStream_t stream)
{
  const int*   ids  = (const int*)  d_in[0];
  const float* emb  = (const float*)d_in[1];
  const float* n0w  = (const float*)d_in[2];
  const float* ipw  = (const float*)d_in[3];
  const float* cw   = (const float*)d_in[4];
  const float* cb   = (const float*)d_in[5];
  const float* xpw  = (const float*)d_in[6];
  const float* dtw  = (const float*)d_in[7];
  const float* dtb  = (const float*)d_in[8];
  const float* alog = (const float*)d_in[9];
  const float* dpar = (const float*)d_in[10];
  const float* opw  = (const float*)d_in[11];
  const float* n1w  = (const float*)d_in[12];
  const float* rw   = (const float*)d_in[13];
  const float* rb   = (const float*)d_in[14];
  const float* f1w  = (const float*)d_in[15];
  const float* f2w  = (const float*)d_in[16];
  const float* fnw  = (const float*)d_in[17];
  float* out = (float*)d_out;
  char* ws = (char*)d_ws;

  // workspace layout (bytes); h1 overlays the dead proj..y span
  size_t o_x       = 0;                          // 8,388,608
  size_t o_xnbf    = o_x + 8388608;              // 4,194,304
  size_t o_ti      = o_xnbf + 4194304;           // 16,384
  size_t o_ts      = o_ti + 16384;               // 16,384
  size_t o_slott   = o_ts + 16384;               // 20,480
  size_t o_tslots  = o_slott + 20480;            // 16,384
  size_t o_tile    = o_tslots + 16384;           // 256
  size_t o_xn      = o_tile + 256;               // 8,388,608
  size_t o_proj    = o_xn + 8388608;             // 33,554,432
  size_t o_uconv   = o_proj + 33554432;          // 16,777,216
  size_t o_xp      = o_uconv + 16777216;         // 786,432
  size_t o_dl      = o_xp + 786432;              // 16,777,216
  size_t o_y       = o_dl + 16777216;            // 16,777,216
  size_t o_yg      = o_y + 16777216;             // 16,777,216
  size_t o_h1      = o_proj;                     // 83,886,080 (overlay, fits in proj..y span)
  size_t o_hidden  = o_yg + 16777216;            // 20,971,520
  size_t o_eo      = o_hidden + 20971520;        // 20,971,520
  size_t o_xnf     = o_eo + 20971520;            // 4,194,304
  // scan carry buffers overlay hidden/eo (dead until after scan): 3 x 8 MB
  size_t o_locfin  = o_hidden;                   // 8,388,608
  size_t o_pst     = o_locfin + 8388608;         // 8,388,608
  size_t o_init    = o_pst + 8388608;            // 8,388,608
  // bf16 emb (65,536,000 B) overlays proj..dl span — dead after silu_mul (h1 is its
  // last reader); live from post-silu_mul conversion until lmhead at the end.
  size_t o_embbf   = o_proj;

  float* x      = (float*)(ws + o_x);
  unsigned short* xnbf = (unsigned short*)(ws + o_xnbf);
  int*   ti     = (int*)(ws + o_ti);
  float* ts     = (float*)(ws + o_ts);
  int*   slott  = (int*)(ws + o_slott);
  int*   tslots = (int*)(ws + o_tslots);
  int*   tile_e = (int*)(ws + o_tile);
  float* xn     = (float*)(ws + o_xn);
  float* proj   = (float*)(ws + o_proj);
  float* uconv  = (float*)(ws + o_uconv);
  float* xp     = (float*)(ws + o_xp);
  float* dl     = (float*)(ws + o_dl);
  float* y      = (float*)(ws + o_y);
  float* yg     = (float*)(ws + o_yg);
  float* h1     = (float*)(ws + o_h1);
  unsigned short* hidden = (unsigned short*)(ws + o_hidden);
  float* eo     = (float*)(ws + o_eo);
  unsigned short* xnf = (unsigned short*)(ws + o_xnf);
  float* locfin = (float*)(ws + o_locfin);
  float* pst    = (float*)(ws + o_pst);
  float* initst = (float*)(ws + o_init);
  unsigned short* embbf = (unsigned short*)(ws + o_embbf);

  embed_rms_k<<<NTOK,256,0,stream>>>(ids, emb, n0w, x, xn);
  // in_proj: [2048,1024] x [4096,1024]^T -> proj [2048,4096]
  gemm_f32k<0><<<dim3(64,32),256,0,stream>>>(xn, HD, ipw, proj, 4096, 4096, HD, nullptr);
  conv_silu_k<<<(NTOK*INNER)/256,256,0,stream>>>(proj, cw, cb, uconv);
  // x_proj: [2048,2048] x [96,2048]^T -> xp [2048,96]
  gemm_f32k<0><<<dim3(2,32),256,0,stream>>>(uconv, INNER, xpw, xp, 96, 96, INNER, nullptr);
  // dt_proj + bias + softplus
  gemm_f32k<1><<<dim3(32,32),256,0,stream>>>(xp, 96, dtw, dl, INNER, INNER, DTR, dtb);
  scan_p1<<<dim3(8,NCH,2),256,0,stream>>>(dl, uconv, xp, alog, locfin, pst);
  scan_p2<<<dim3(8,SDIM,2),256,0,stream>>>(locfin, pst, initst);
  scan_p3<<<dim3(8,NCH,2),256,0,stream>>>(dl, uconv, xp, alog, dpar, initst, y);
  ygate_k<<<(NTOK*INNER)/256,256,0,stream>>>(y, proj, yg);
  // out_proj + residual
  gemm_f32k<2><<<dim3(16,32),256,0,stream>>>(yg, INNER, opw, x, HD, HD, INNER, nullptr);
  rms_router_k<<<NTOK,256,0,stream>>>(x, n1w, rw, rb, xnbf, ti, ts);
  route_build_k<<<1,256,0,stream>>>(ti, ts, slott, tslots, tile_e);
  // fc1: gathered xn (bf16) x fc1_w[e] -> h1 [5120,4096]
  gemm_bf16k<true,true><<<dim3(32,MAX_TILES),256,0,stream>>>(
      xnbf, HD, slott, f1w, 4096LL*1024LL, tile_e, h1, 4096, HD);
  silu_mul_k<<<(SLOT_CAP*FFN)/256,256,0,stream>>>(h1, hidden);
  // h1/proj span now dead -> convert emb to bf16 there for the LM head
  f2bf_arr_k<<<(VDIM*HD/8)/256,256,0,stream>>>(emb, embbf);
  // fc2: hidden (bf16) x fc2_w[e] -> eo [5120,1024]
  gemm_bf16k<false,true><<<dim3(8,MAX_TILES),256,0,stream>>>(
      hidden, FFN, nullptr, f2w, 1024LL*2048LL, tile_e, eo, HD, FFN);
  combine_rms_k<<<NTOK,256,0,stream>>>(x, eo, tslots, ts, fnw, xnf);
  // LM head: xnf (bf16) x embbf (bf16) -> out [2048,32000]
  lmhead_k<<<4000,256,0,stream>>>(xnf, embbf, out);
}

// Round 3
// 1223.642 us; speedup vs baseline: 1.2537x; 1.1666x over previous
//
#include <hip/hip_runtime.h>
#include <cstdint>

#define HD 1024
#define INNER 2048
#define NTOK 2048
#define SEQL 1024
#define SDIM 16
#define DTR 64
#define VDIM 32000
#define FFN 2048
#define EPSV 1e-5f
#define SLOT_CAP 5120
#define MAX_TILES 40
#define NCH 32
#define CLEN 32

typedef __attribute__((ext_vector_type(8))) short short8;
typedef __attribute__((ext_vector_type(4))) float f32x4;

__device__ __forceinline__ unsigned short f2bf(float f){
  unsigned int u = __float_as_uint(f);
  u += 0x7FFF + ((u >> 16) & 1);
  return (unsigned short)(u >> 16);
}
__device__ __forceinline__ float bf2f(unsigned short h){
  return __uint_as_float(((unsigned int)h) << 16);
}
// split f32 into bf16 high + bf16 low (residual); a ~= h + l to ~2^-17 rel
__device__ __forceinline__ void splitbf(float v, unsigned short &h, unsigned short &l){
  h = f2bf(v);
  l = f2bf(v - bf2f(h));
}
__device__ __forceinline__ float sigm(float x){ return 1.f/(1.f+__expf(-x)); }

__device__ __forceinline__ void gload16(const unsigned short* g, unsigned short* l){
  __builtin_amdgcn_global_load_lds(
    (const __attribute__((address_space(1))) unsigned int*)g,
    (__attribute__((address_space(3))) unsigned int*)l, 16, 0, 0);
}

__device__ __forceinline__ float block_sum(float v, float* sb){
  #pragma unroll
  for (int m=32;m>=1;m>>=1) v += __shfl_xor(v, m, 64);
  int lane = threadIdx.x & 63, w = threadIdx.x >> 6;
  if (lane==0) sb[w]=v;
  __syncthreads();
  float s = sb[0]+sb[1]+sb[2]+sb[3];
  __syncthreads();
  return s;
}

// ---------------- embed + rms0 (emit split-bf16 xn) ----------------
__global__ __launch_bounds__(256) void embed_rms_k(
  const int* __restrict__ ids, const float* __restrict__ emb,
  const float* __restrict__ n0w, float* __restrict__ x,
  unsigned short* __restrict__ xnh, unsigned short* __restrict__ xnl)
{
  __shared__ float sb[4];
  int tok = blockIdx.x, t = threadIdx.x;
  int id = ids[tok];
  float4 v = *(const float4*)(emb + (size_t)id*HD + t*4);
  *(float4*)(x + (size_t)tok*HD + t*4) = v;
  float tot = block_sum(v.x*v.x+v.y*v.y+v.z*v.z+v.w*v.w, sb);
  float rs = rsqrtf(tot/(float)HD + EPSV);
  float4 w = *(const float4*)(n0w + t*4);
  float4 o; o.x=v.x*rs*w.x; o.y=v.y*rs*w.y; o.z=v.z*rs*w.z; o.w=v.w*rs*w.w;
  ushort4 h, l;
  splitbf(o.x, h.x, l.x); splitbf(o.y, h.y, l.y);
  splitbf(o.z, h.z, l.z); splitbf(o.w, h.w, l.w);
  *(ushort4*)(xnh + (size_t)tok*HD + t*4) = h;
  *(ushort4*)(xnl + (size_t)tok*HD + t*4) = l;
}

// ---------------- f32 -> split bf16 bulk (weights) ----------------
__global__ __launch_bounds__(256) void split_bf_k(
  const float* __restrict__ in, unsigned short* __restrict__ h, unsigned short* __restrict__ l)
{
  size_t i = (size_t)(blockIdx.x*256 + threadIdx.x) * 8;
  const float4* p = (const float4*)(in + i);
  float4 a = p[0], b = p[1];
  ushort4 h0,l0,h1,l1;
  splitbf(a.x,h0.x,l0.x); splitbf(a.y,h0.y,l0.y); splitbf(a.z,h0.z,l0.z); splitbf(a.w,h0.w,l0.w);
  splitbf(b.x,h1.x,l1.x); splitbf(b.y,h1.y,l1.y); splitbf(b.z,h1.z,l1.z); splitbf(b.w,h1.w,l1.w);
  *(ushort4*)(h + i)     = h0;
  *(ushort4*)(h + i + 4) = h1;
  *(ushort4*)(l + i)     = l0;
  *(ushort4*)(l + i + 4) = l1;
}

// ---------------- split-bf16 MFMA GEMM: C[M,N] = A[M,K]*B[N,K]^T, f32-accurate ----------
// 3-term: ah@bh + ah@bl + al@bh (al@bl ~ 2^-18, dropped). Same dbuf global_load_lds +
// slot-XOR swizzle structure as lmhead_k (verified). EPI 0: store. EPI 2: += C.
template<int EPI>
__global__ __launch_bounds__(256) void gemm_bfsplit_k(
  const unsigned short* __restrict__ Ah, const unsigned short* __restrict__ Al,
  const unsigned short* __restrict__ Bh, const unsigned short* __restrict__ Bl,
  float* __restrict__ C, int ldc, int K)
{
  __shared__ __align__(16) unsigned short AH[2][128][32];
  __shared__ __align__(16) unsigned short AL[2][128][32];
  __shared__ __align__(16) unsigned short BH[2][128][32];
  __shared__ __align__(16) unsigned short BL[2][128][32];
  int mt = blockIdx.y, nt = blockIdx.x;
  int m0 = mt*128, n0 = nt*128;
  int t = threadIdx.x, w = t >> 6, lane = t & 63;
  int wm = (w >> 1) * 64, wn = (w & 1) * 64;
  int lr = lane & 15, quad = lane >> 4;
  int row0 = w*16 + (lane>>2);
  int koff = ((lane&3) ^ ((lane>>3)&3)) * 8;   // pre-swizzled 16B k-chunk
  int p0 = (w*1024 + lane*16) >> 1;            // linear LDS dest (ushort units)
  int p1 = p0 + 2048;
  size_t a0 = (size_t)(m0 + row0)*K + koff;
  size_t b0 = (size_t)(n0 + row0)*K + koff;
  const unsigned short* gAh0 = Ah + a0; const unsigned short* gAh1 = gAh0 + (size_t)64*K;
  const unsigned short* gAl0 = Al + a0; const unsigned short* gAl1 = gAl0 + (size_t)64*K;
  const unsigned short* gBh0 = Bh + b0; const unsigned short* gBh1 = gBh0 + (size_t)64*K;
  const unsigned short* gBl0 = Bl + b0; const unsigned short* gBl1 = gBl0 + (size_t)64*K;
  int sq = (quad ^ ((lr>>1)&3)) * 8;           // swizzled slot on read side

  f32x4 acc[4][4] = {};

#define STG(bi,k0) \
    gload16(gAh0+(k0), &AH[bi][0][0]+p0); gload16(gAh1+(k0), &AH[bi][0][0]+p1); \
    gload16(gAl0+(k0), &AL[bi][0][0]+p0); gload16(gAl1+(k0), &AL[bi][0][0]+p1); \
    gload16(gBh0+(k0), &BH[bi][0][0]+p0); gload16(gBh1+(k0), &BH[bi][0][0]+p1); \
    gload16(gBl0+(k0), &BL[bi][0][0]+p0); gload16(gBl1+(k0), &BL[bi][0][0]+p1);

#define CMP(bi) { \
    short8 ah[4], al[4], bh[4], bl[4]; \
    _Pragma("unroll") \
    for (int mi=0;mi<4;mi++){ \
      ah[mi] = *(const short8*)&AH[bi][wm + mi*16 + lr][sq]; \
      al[mi] = *(const short8*)&AL[bi][wm + mi*16 + lr][sq]; } \
    _Pragma("unroll") \
    for (int ni=0;ni<4;ni++){ \
      bh[ni] = *(const short8*)&BH[bi][wn + ni*16 + lr][sq]; \
      bl[ni] = *(const short8*)&BL[bi][wn + ni*16 + lr][sq]; } \
    _Pragma("unroll") \
    for (int mi=0;mi<4;mi++) \
      _Pragma("unroll") \
      for (int ni=0;ni<4;ni++){ \
        acc[mi][ni] = __builtin_amdgcn_mfma_f32_16x16x32_bf16(al[mi], bh[ni], acc[mi][ni], 0, 0, 0); \
        acc[mi][ni] = __builtin_amdgcn_mfma_f32_16x16x32_bf16(ah[mi], bl[ni], acc[mi][ni], 0, 0, 0); \
        acc[mi][ni] = __builtin_amdgcn_mfma_f32_16x16x32_bf16(ah[mi], bh[ni], acc[mi][ni], 0, 0, 0); } }

  STG(0, 0);
  __syncthreads();
  for (int k0 = 0; k0 < K; k0 += 64){
    STG(1, k0+32);
    CMP(0);
    __syncthreads();
    if (k0 + 64 < K) { STG(0, k0+64); }
    CMP(1);
    __syncthreads();
  }
#undef STG
#undef CMP

  #pragma unroll
  for (int mi=0;mi<4;mi++){
    int rbase = m0 + wm + mi*16 + quad*4;
    #pragma unroll
    for (int ni=0;ni<4;ni++){
      int col = n0 + wn + ni*16 + lr;
      float* cp = C + (size_t)rbase*ldc + col;
      #pragma unroll
      for (int r=0;r<4;r++){
        float v = acc[mi][ni][r];
        if (EPI==2) v += cp[(size_t)r*ldc];
        cp[(size_t)r*ldc] = v;
      }
    }
  }
}

// ---------------- generic fp32 GEMM (kept for small x_proj / dt_proj) ----------------
template<int EPI>
__global__ __launch_bounds__(256) void gemm_f32k(
  const float* __restrict__ A, int lda,
  const float* __restrict__ B,
  float* __restrict__ C, int ldc,
  int N, int K, const float* __restrict__ bias)
{
  __shared__ float As[16][68];
  __shared__ float Bs[16][68];
  int m0 = blockIdx.y*64, n0 = blockIdx.x*64;
  int t = threadIdx.x, tm = t & 15, tn = t >> 4;
  float acc[4][4] = {};
  int srow = t >> 2, skq = (t & 3) * 4;
  const float* arow = A + (size_t)(m0 + srow)*lda + skq;
  int nrow = n0 + srow;
  const float* brow = B + (size_t)nrow*K + skq;
  bool bok = nrow < N;
  for (int k0 = 0; k0 < K; k0 += 16) {
    float4 a = *(const float4*)(arow + k0);
    float4 b = bok ? *(const float4*)(brow + k0) : make_float4(0.f,0.f,0.f,0.f);
    __syncthreads();
    As[skq+0][srow]=a.x; As[skq+1][srow]=a.y; As[skq+2][srow]=a.z; As[skq+3][srow]=a.w;
    Bs[skq+0][srow]=b.x; Bs[skq+1][srow]=b.y; Bs[skq+2][srow]=b.z; Bs[skq+3][srow]=b.w;
    __syncthreads();
    #pragma unroll
    for (int k=0;k<16;k++){
      const float4 av = *(const float4*)&As[k][tm*4];
      const float4 bv = *(const float4*)&Bs[k][tn*4];
      float am[4] = {av.x, av.y, av.z, av.w};
      float bn[4] = {bv.x, bv.y, bv.z, bv.w};
      #pragma unroll
      for (int i=0;i<4;i++)
        #pragma unroll
        for (int j=0;j<4;j++)
          acc[i][j] += am[i]*bn[j];
    }
  }
  #pragma unroll
  for (int i=0;i<4;i++){
    int row = m0 + tm*4 + i;
    #pragma unroll
    for (int j=0;j<4;j++){
      int col = n0 + tn*4 + j;
      if (col < N){
        float v = acc[i][j];
        if (EPI==1){ v += bias[col]; v = (v > 20.f) ? v : log1pf(expf(v)); }
        if (EPI==2){ v += C[(size_t)row*ldc + col]; }
        C[(size_t)row*ldc + col] = v;
      }
    }
  }
}

// ---------------- causal depthwise conv (K=4) + silu ----------------
__global__ __launch_bounds__(256) void conv_silu_k(
  const float* __restrict__ proj, const float* __restrict__ cw,
  const float* __restrict__ cb, float* __restrict__ uc)
{
  int idx = blockIdx.x*256 + threadIdx.x;     // over B*L*INNER
  int c = idx & (INNER-1);
  int l = (idx >> 11) & (SEQL-1);
  int b = idx >> 21;
  float s = cb[c];
  #pragma unroll
  for (int k=0;k<4;k++){
    int ll = l + k - 3;
    if (ll >= 0) s += proj[(size_t)(b*SEQL + ll)*4096 + c] * cw[c*4+k];
  }
  uc[idx] = s * sigm(s);
}

// ---------------- chunked selective scan: pass 1 ----------------
__global__ __launch_bounds__(256) void scan_p1(
  const float* __restrict__ dl, const float* __restrict__ uc,
  const float* __restrict__ xp, const float* __restrict__ alog,
  float* __restrict__ locfin, float* __restrict__ Pst)
{
  int c = blockIdx.x*256 + threadIdx.x;
  int chunk = blockIdx.y, b = blockIdx.z;
  float a[SDIM];
  #pragma unroll
  for (int s=0;s<SDIM;s++) a[s] = -expf(alog[c*SDIM+s]);
  float st[SDIM] = {};
  float P[SDIM];
  #pragma unroll
  for (int s=0;s<SDIM;s++) P[s] = 1.f;
  size_t base = (size_t)b*SEQL + chunk*CLEN;
  #pragma unroll 2
  for (int l=0;l<CLEN;l++){
    size_t tix = base + l;
    float d = dl[tix*INNER + c];
    float u = uc[tix*INNER + c];
    const float* bc = xp + tix*96 + 64;
    float w = d*u;
    #pragma unroll
    for (int s=0;s<SDIM;s++){
      float p = __expf(d*a[s]);
      st[s] = p*st[s] + w*bc[s];
      P[s] *= p;
    }
  }
  size_t cb = (size_t)(b*NCH + chunk)*SDIM*INNER + c;
  #pragma unroll
  for (int s=0;s<SDIM;s++){
    locfin[cb + (size_t)s*INNER] = st[s];
    Pst[cb + (size_t)s*INNER] = P[s];
  }
}

// ---------------- pass 2 ----------------
__global__ __launch_bounds__(256) void scan_p2(
  const float* __restrict__ locfin, const float* __restrict__ Pst,
  float* __restrict__ initst)
{
  int c = blockIdx.x*256 + threadIdx.x;
  int s = blockIdx.y, b = blockIdx.z;
  float carry = 0.f;
  #pragma unroll 4
  for (int chunk=0; chunk<NCH; chunk++){
    size_t idx = ((size_t)(b*NCH + chunk)*SDIM + s)*INNER + c;
    initst[idx] = carry;
    carry = Pst[idx]*carry + locfin[idx];
  }
}

// ---------------- pass 3 ----------------
__global__ __launch_bounds__(256) void scan_p3(
  const float* __restrict__ dl, const float* __restrict__ uc,
  const float* __restrict__ xp, const float* __restrict__ alog,
  const float* __restrict__ dpar, const float* __restrict__ initst,
  float* __restrict__ y)
{
  int c = blockIdx.x*256 + threadIdx.x;
  int chunk = blockIdx.y, b = blockIdx.z;
  float a[SDIM], st[SDIM];
  #pragma unroll
  for (int s=0;s<SDIM;s++) a[s] = -expf(alog[c*SDIM+s]);
  size_t cb = (size_t)(b*NCH + chunk)*SDIM*INNER + c;
  #pragma unroll
  for (int s=0;s<SDIM;s++) st[s] = initst[cb + (size_t)s*INNER];
  float dv = dpar[c];
  size_t base = (size_t)b*SEQL + chunk*CLEN;
  #pragma unroll 2
  for (int l=0;l<CLEN;l++){
    size_t tix = base + l;
    float d = dl[tix*INNER + c];
    float u = uc[tix*INNER + c];
    const float* bc = xp + tix*96 + 64;
    float w = d*u, acc = 0.f;
    #pragma unroll
    for (int s=0;s<SDIM;s++){
      float p = __expf(d*a[s]);
      st[s] = p*st[s] + w*bc[s];
      acc += st[s]*bc[16+s];
    }
    y[tix*INNER + c] = acc + u*dv;
  }
}

// ---------------- y * silu(gate) -> split bf16 ----------------
__global__ __launch_bounds__(256) void ygate_k(
  const float* __restrict__ y, const float* __restrict__ proj,
  unsigned short* __restrict__ ygh, unsigned short* __restrict__ ygl)
{
  int idx = blockIdx.x*256 + threadIdx.x;
  int c = idx & (INNER-1); int t_ = idx >> 11;
  float g = proj[(size_t)t_*4096 + 2048 + c];
  float v = y[idx] * g * sigm(g);
  unsigned short h, l;
  splitbf(v, h, l);
  ygh[idx] = h; ygl[idx] = l;
}

// ---------------- rms1 + router (softmax top2) ----------------
__global__ __launch_bounds__(256) void rms_router_k(
  const float* __restrict__ x, const float* __restrict__ n1w,
  const float* __restrict__ rw, const float* __restrict__ rb,
  unsigned short* __restrict__ xnbf, int* __restrict__ ti, float* __restrict__ ts)
{
  __shared__ float sb[4];
  __shared__ float sb8[8][4];
  int tok = blockIdx.x, t = threadIdx.x;
  float4 v = *(const float4*)(x + (size_t)tok*HD + t*4);
  float tot = block_sum(v.x*v.x+v.y*v.y+v.z*v.z+v.w*v.w, sb);
  float rs = rsqrtf(tot/(float)HD + EPSV);
  float4 w = *(const float4*)(n1w + t*4);
  float4 xv; xv.x=v.x*rs*w.x; xv.y=v.y*rs*w.y; xv.z=v.z*rs*w.z; xv.w=v.w*rs*w.w;
  ushort4 o; o.x=f2bf(xv.x); o.y=f2bf(xv.y); o.z=f2bf(xv.z); o.w=f2bf(xv.w);
  *(ushort4*)(xnbf + (size_t)tok*HD + t*4) = o;
  float pe[8];
  #pragma unroll
  for (int e=0;e<8;e++){
    const float4 r4 = *(const float4*)(rw + (size_t)e*HD + t*4);
    pe[e] = xv.x*r4.x + xv.y*r4.y + xv.z*r4.z + xv.w*r4.w;
  }
  int lane = t & 63, wv = t >> 6;
  #pragma unroll
  for (int e=0;e<8;e++){
    float s = pe[e];
    #pragma unroll
    for (int m=32;m>=1;m>>=1) s += __shfl_xor(s, m, 64);
    if (lane==0) sb8[e][wv] = s;
  }
  __syncthreads();
  if (t==0){
    float lg[8], mx = -1e30f;
    for (int e=0;e<8;e++){ lg[e] = sb8[e][0]+sb8[e][1]+sb8[e][2]+sb8[e][3] + rb[e]; mx = fmaxf(mx, lg[e]); }
    float ex[8], sum=0.f;
    for (int e=0;e<8;e++){ ex[e]=expf(lg[e]-mx); sum+=ex[e]; }
    float inv = 1.f/sum;
    int i0=0; float p0=-1.f;
    for (int e=0;e<8;e++){ float p=ex[e]*inv; if (p>p0){p0=p;i0=e;} }
    int i1=-1; float p1=-1.f;
    for (int e=0;e<8;e++){ if (e==i0) continue; float p=ex[e]*inv; if (p>p1){p1=p;i1=e;} }
    ti[2*tok]=i0; ti[2*tok+1]=i1; ts[2*tok]=p0; ts[2*tok+1]=p1;
  }
}

// ---------------- routing ----------------
__global__ void route_build_k(const int* __restrict__ ti, const float* __restrict__ ts,
  int* __restrict__ slot_token, int* __restrict__ tok_slots, int* __restrict__ tile_expert)
{
  __shared__ int cnt[8], cur[8];
  int t = threadIdx.x;
  if (t < 8) cnt[t] = 0;
  __syncthreads();
  for (int tok = t; tok < NTOK; tok += 256){
    atomicAdd(&cnt[ti[2*tok]], 1);
    atomicAdd(&cnt[ti[2*tok+1]], 1);
  }
  __syncthreads();
  if (t == 0){
    int off = 0, tile = 0;
    for (int e=0;e<8;e++){
      cur[e] = off;
      int nt2 = (cnt[e] + 127) >> 7;
      for (int j=0;j<nt2;j++) tile_expert[tile++] = e;
      off += nt2 << 7;
    }
    while (tile < MAX_TILES) tile_expert[tile++] = -1;
  }
  __syncthreads();
  for (int i = t; i < SLOT_CAP; i += 256) slot_token[i] = -1;
  __syncthreads();
  for (int tok = t; tok < NTOK; tok += 256){
    #pragma unroll
    for (int j=0;j<2;j++){
      int e = ti[2*tok+j];
      int p = atomicAdd(&cur[e], 1);
      slot_token[p] = tok;
      tok_slots[2*tok+j] = p;
    }
  }
}

// ---------------- bf16 MFMA GEMM (fc1/fc2 path, B f32 converted on the fly) ----------------
template<bool GATHER, bool EXPERT>
__global__ __launch_bounds__(256) void gemm_bf16k(
  const unsigned short* __restrict__ A, int lda,
  const int* __restrict__ slot_token,
  const float* __restrict__ B0, long long expert_stride,
  const int* __restrict__ tile_expert,
  float* __restrict__ C, int ldc, int K)
{
  int mt = blockIdx.y, nt = blockIdx.x;
  const float* Bp = B0;
  if (EXPERT){
    int e = tile_expert[mt];
    if (e < 0) return;
    Bp = B0 + (long long)e * expert_stride;
  }
  int m0 = mt*128, n0 = nt*128;
  __shared__ unsigned short As[128][40];
  __shared__ unsigned short Bs[128][40];
  int t = threadIdx.x;
  int w = t >> 6, lane = t & 63;
  int wm = (w >> 1) * 64, wn = (w & 1) * 64;
  int lr = lane & 15, quad = lane >> 4;
  f32x4 acc[4][4] = {};

  int arow = t >> 1;
  int ahalf = t & 1;
  const unsigned short* asrc = nullptr;
  bool avalid = true;
  if (GATHER){
    int tok = slot_token[m0 + arow];
    avalid = (tok >= 0);
    if (avalid) asrc = A + (size_t)tok * lda;
  } else {
    asrc = A + (size_t)(m0 + arow) * lda;
  }
  const float* bsrc = Bp + (size_t)(n0 + arow) * K;

  for (int k0 = 0; k0 < K; k0 += 32){
    uint4 av0 = make_uint4(0,0,0,0), av1 = make_uint4(0,0,0,0);
    if (avalid){
      const uint4* p = (const uint4*)(asrc + k0 + ahalf*16);
      av0 = p[0]; av1 = p[1];
    }
    const float4* q = (const float4*)(bsrc + k0 + ahalf*16);
    float4 b0 = q[0], b1 = q[1], b2 = q[2], b3 = q[3];
    uint4 w0, w1;
    w0.x = (uint32_t)f2bf(b0.x) | ((uint32_t)f2bf(b0.y)<<16);
    w0.y = (uint32_t)f2bf(b0.z) | ((uint32_t)f2bf(b0.w)<<16);
    w0.z = (uint32_t)f2bf(b1.x) | ((uint32_t)f2bf(b1.y)<<16);
    w0.w = (uint32_t)f2bf(b1.z) | ((uint32_t)f2bf(b1.w)<<16);
    w1.x = (uint32_t)f2bf(b2.x) | ((uint32_t)f2bf(b2.y)<<16);
    w1.y = (uint32_t)f2bf(b2.z) | ((uint32_t)f2bf(b2.w)<<16);
    w1.z = (uint32_t)f2bf(b3.x) | ((uint32_t)f2bf(b3.y)<<16);
    w1.w = (uint32_t)f2bf(b3.z) | ((uint32_t)f2bf(b3.w)<<16);
    __syncthreads();
    *(uint4*)&As[arow][ahalf*16]     = av0;
    *(uint4*)&As[arow][ahalf*16 + 8] = av1;
    *(uint4*)&Bs[arow][ahalf*16]     = w0;
    *(uint4*)&Bs[arow][ahalf*16 + 8] = w1;
    __syncthreads();
    short8 af[4], bf[4];
    #pragma unroll
    for (int mi=0;mi<4;mi++) af[mi] = *(const short8*)&As[wm + mi*16 + lr][quad*8];
    #pragma unroll
    for (int ni=0;ni<4;ni++) bf[ni] = *(const short8*)&Bs[wn + ni*16 + lr][quad*8];
    #pragma unroll
    for (int mi=0;mi<4;mi++)
      #pragma unroll
      for (int ni=0;ni<4;ni++)
        acc[mi][ni] = __builtin_amdgcn_mfma_f32_16x16x32_bf16(af[mi], bf[ni], acc[mi][ni], 0, 0, 0);
  }
  #pragma unroll
  for (int mi=0;mi<4;mi++){
    int rbase = m0 + wm + mi*16 + quad*4;
    #pragma unroll
    for (int ni=0;ni<4;ni++){
      int col = n0 + wn + ni*16 + lr;
      float* cp = C + (size_t)rbase*ldc + col;
      #pragma unroll
      for (int r=0;r<4;r++) cp[(size_t)r*ldc] = acc[mi][ni][r];
    }
  }
}

// ---------------- f32 -> bf16 bulk convert (for emb) ----------------
__global__ __launch_bounds__(256) void f2bf_arr_k(
  const float* __restrict__ in, unsigned short* __restrict__ out)
{
  size_t i = (size_t)(blockIdx.x*256 + threadIdx.x) * 8;
  const float4* p = (const float4*)(in + i);
  float4 a = p[0], b = p[1];
  ushort4 o0, o1;
  o0.x=f2bf(a.x); o0.y=f2bf(a.y); o0.z=f2bf(a.z); o0.w=f2bf(a.w);
  o1.x=f2bf(b.x); o1.y=f2bf(b.y); o1.z=f2bf(b.z); o1.w=f2bf(b.w);
  *(ushort4*)(out + i)     = o0;
  *(ushort4*)(out + i + 4) = o1;
}

// ---------------- LM head: both-bf16 MFMA GEMM, dbuf global_load_lds + slot-XOR swizzle ----
__global__ __launch_bounds__(256) void lmhead_k(
  const unsigned short* __restrict__ A,
  const unsigned short* __restrict__ B,
  float* __restrict__ C)
{
  __shared__ __align__(16) unsigned short As0[128][32];
  __shared__ __align__(16) unsigned short Bs0[128][32];
  __shared__ __align__(16) unsigned short As1[128][32];
  __shared__ __align__(16) unsigned short Bs1[128][32];
  int orig = blockIdx.x;                 // 4000 blocks, 4000 % 8 == 0
  int swz = (orig & 7)*500 + (orig >> 3);
  int mt = swz & 15, nt = swz >> 4;      // mt in [0,16), nt in [0,250)
  int m0 = mt*128, n0 = nt*128;
  int t = threadIdx.x, w = t >> 6, lane = t & 63;
  int wm = (w >> 1) * 64, wn = (w & 1) * 64;
  int lr = lane & 15, quad = lane >> 4;

  int row0 = w*16 + (lane>>2);
  int koff = ((lane&3) ^ ((lane>>3)&3)) * 8;
  int p0 = (w*1024 + lane*16) >> 1;
  int p1 = p0 + 2048;
  const unsigned short* gA0 = A + (size_t)(m0 + row0)*HD + koff;
  const unsigned short* gA1 = gA0 + (size_t)64*HD;
  const unsigned short* gB0 = B + (size_t)(n0 + row0)*HD + koff;
  const unsigned short* gB1 = gB0 + (size_t)64*HD;

  int sq = (quad ^ ((lr>>1)&3)) * 8;

  f32x4 acc[4][4] = {};

#define STAGE(AS,BS,k0) \
    gload16(gA0 + (k0), &AS[0][0] + p0); \
    gload16(gA1 + (k0), &AS[0][0] + p1); \
    gload16(gB0 + (k0), &BS[0][0] + p0); \
    gload16(gB1 + (k0), &BS[0][0] + p1);

#define COMPUTE(AS,BS) { \
    short8 af[4], bf[4]; \
    _Pragma("unroll") \
    for (int mi=0;mi<4;mi++) af[mi] = *(const short8*)&AS[wm + mi*16 + lr][sq]; \
    _Pragma("unroll") \
    for (int ni=0;ni<4;ni++) bf[ni] = *(const short8*)&BS[wn + ni*16 + lr][sq]; \
    _Pragma("unroll") \
    for (int mi=0;mi<4;mi++) \
      _Pragma("unroll") \
      for (int ni=0;ni<4;ni++) \
        acc[mi][ni] = __builtin_amdgcn_mfma_f32_16x16x32_bf16(af[mi], bf[ni], acc[mi][ni], 0, 0, 0); }

  STAGE(As0,Bs0, 0);
  __syncthreads();
  for (int k0 = 0; k0 < HD; k0 += 64){
    STAGE(As1,Bs1, k0+32);
    COMPUTE(As0,Bs0);
    __syncthreads();
    if (k0 + 64 < HD) { STAGE(As0,Bs0, k0+64); }
    COMPUTE(As1,Bs1);
    __syncthreads();
  }
#undef STAGE
#undef COMPUTE

  #pragma unroll
  for (int mi=0;mi<4;mi++){
    int rbase = m0 + wm + mi*16 + quad*4;
    #pragma unroll
    for (int ni=0;ni<4;ni++){
      int col = n0 + wn + ni*16 + lr;
      float* cp = C + (size_t)rbase*VDIM + col;
      #pragma unroll
      for (int r=0;r<4;r++) cp[(size_t)r*VDIM] = acc[mi][ni][r];
    }
  }
}

// ---------------- silu(h1a)*h1b -> hidden bf16 ----------------
__global__ __launch_bounds__(256) void silu_mul_k(
  const float* __restrict__ h1, unsigned short* __restrict__ hidden)
{
  int idx = blockIdx.x*256 + threadIdx.x;   // over SLOT_CAP*FFN
  int f = idx & (FFN-1); int slot = idx >> 11;
  float a = h1[(size_t)slot*2*FFN + f];
  float b = h1[(size_t)slot*2*FFN + FFN + f];
  hidden[idx] = f2bf(a*sigm(a)*b);
}

// ---------------- combine experts + final rms -> xnf bf16 ----------------
__global__ __launch_bounds__(256) void combine_rms_k(
  const float* __restrict__ x, const float* __restrict__ eo,
  const int* __restrict__ tok_slots, const float* __restrict__ ts,
  const float* __restrict__ fw, unsigned short* __restrict__ xnf)
{
  __shared__ float sb[4];
  int tok = blockIdx.x, t = threadIdx.x;
  int p0 = tok_slots[2*tok], p1 = tok_slots[2*tok+1];
  float s0 = ts[2*tok], s1 = ts[2*tok+1];
  float4 v  = *(const float4*)(x  + (size_t)tok*HD + t*4);
  float4 e0 = *(const float4*)(eo + (size_t)p0*HD + t*4);
  float4 e1 = *(const float4*)(eo + (size_t)p1*HD + t*4);
  v.x += s0*e0.x + s1*e1.x;
  v.y += s0*e0.y + s1*e1.y;
  v.z += s0*e0.z + s1*e1.z;
  v.w += s0*e0.w + s1*e1.w;
  float tot = block_sum(v.x*v.x+v.y*v.y+v.z*v.z+v.w*v.w, sb);
  float rs = rsqrtf(tot/(float)HD + EPSV);
  float4 w = *(const float4*)(fw + t*4);
  ushort4 o;
  o.x=f2bf(v.x*rs*w.x); o.y=f2bf(v.y*rs*w.y); o.z=f2bf(v.z*rs*w.z); o.w=f2bf(v.w*rs*w.w);
  *(ushort4*)(xnf + (size_t)tok*HD + t*4) = o;
}

extern "C" void kernel_launch(void* const* d_in, const int* in_sizes, int n_in,
                              void* d_out, int out_size, void* d_ws, size_t ws_size,
                              hipStream_t stream)
{
  const int*   ids  = (const int*)  d_in[0];
  const float* emb  = (const float*)d_in[1];
  const float* n0w  = (const float*)d_in[2];
  const float* ipw  = (const float*)d_in[3];
  const float* cw   = (const float*)d_in[4];
  const float* cb   = (const float*)d_in[5];
  const float* xpw  = (const float*)d_in[6];
  const float* dtw  = (const float*)d_in[7];
  const float* dtb  = (const float*)d_in[8];
  const float* alog = (const float*)d_in[9];
  const float* dpar = (const float*)d_in[10];
  const float* opw  = (const float*)d_in[11];
  const float* n1w  = (const float*)d_in[12];
  const float* rw   = (const float*)d_in[13];
  const float* rb   = (const float*)d_in[14];
  const float* f1w  = (const float*)d_in[15];
  const float* f2w  = (const float*)d_in[16];
  const float* fnw  = (const float*)d_in[17];
  float* out = (float*)d_out;
  char* ws = (char*)d_ws;

  // workspace layout (bytes)
  size_t o_x       = 0;                          // 8,388,608
  size_t o_xnbf    = o_x + 8388608;              // 4,194,304
  size_t o_ti      = o_xnbf + 4194304;           // 16,384
  size_t o_ts      = o_ti + 16384;               // 16,384
  size_t o_slott   = o_ts + 16384;               // 20,480
  size_t o_tslots  = o_slott + 20480;            // 16,384
  size_t o_tile    = o_tslots + 16384;           // 256
  size_t o_xn      = o_tile + 256;               // 8,388,608 (xnh+xnl; later oph+opl)
  size_t o_proj    = o_xn + 8388608;             // 33,554,432
  size_t o_uconv   = o_proj + 33554432;          // 16,777,216 (iph+ipl until conv writes it)
  size_t o_xp      = o_uconv + 16777216;         // 786,432
  size_t o_dl      = o_xp + 786432;              // 16,777,216
  size_t o_y       = o_dl + 16777216;            // 16,777,216
  size_t o_yg      = o_y + 16777216;             // 16,777,216 (ygh+ygl)
  size_t o_h1      = o_proj;                     // 83,886,080 (overlay, fits in proj..y span)
  size_t o_hidden  = o_yg + 16777216;            // 20,971,520
  size_t o_eo      = o_hidden + 20971520;        // 20,971,520
  size_t o_xnf     = o_eo + 20971520;            // 4,194,304
  // scan carry buffers overlay hidden/eo (dead until after scan): 3 x 8 MB
  size_t o_locfin  = o_hidden;                   // 8,388,608
  size_t o_pst     = o_locfin + 8388608;         // 8,388,608
  size_t o_init    = o_pst + 8388608;            // 8,388,608
  // bf16 emb (65,536,000 B) overlays proj..dl span after silu_mul (h1 dead then)
  size_t o_embbf   = o_proj;
  // split-bf16 operand overlays:
  size_t o_xnh     = o_xn;                       // 4,194,304 (2048x1024 bf16)
  size_t o_xnl     = o_xn + 4194304;             // 4,194,304
  size_t o_iph     = o_uconv;                    // 8,388,608 (4096x1024 bf16)
  size_t o_ipl     = o_uconv + 8388608;          // 8,388,608
  size_t o_oph     = o_xn;                       // 4,194,304 (1024x2048 bf16; after in_proj)
  size_t o_opl     = o_xn + 4194304;             // 4,194,304
  size_t o_ygh     = o_yg;                       // 8,388,608 (2048x2048 bf16)
  size_t o_ygl     = o_yg + 8388608;             // 8,388,608

  float* x      = (float*)(ws + o_x);
  unsigned short* xnbf = (unsigned short*)(ws + o_xnbf);
  int*   ti     = (int*)(ws + o_ti);
  float* ts     = (float*)(ws + o_ts);
  int*   slott  = (int*)(ws + o_slott);
  int*   tslots = (int*)(ws + o_tslots);
  int*   tile_e = (int*)(ws + o_tile);
  float* proj   = (float*)(ws + o_proj);
  float* uconv  = (float*)(ws + o_uconv);
  float* xp     = (float*)(ws + o_xp);
  float* dl     = (float*)(ws + o_dl);
  float* y      = (float*)(ws + o_y);
  float* h1     = (float*)(ws + o_h1);
  unsigned short* hidden = (unsigned short*)(ws + o_hidden);
  float* eo     = (float*)(ws + o_eo);
  unsigned short* xnf = (unsigned short*)(ws + o_xnf);
  float* locfin = (float*)(ws + o_locfin);
  float* pst    = (float*)(ws + o_pst);
  float* initst = (float*)(ws + o_init);
  unsigned short* embbf = (unsigned short*)(ws + o_embbf);
  unsigned short* xnh = (unsigned short*)(ws + o_xnh);
  unsigned short* xnl = (unsigned short*)(ws + o_xnl);
  unsigned short* iph = (unsigned short*)(ws + o_iph);
  unsigned short* ipl = (unsigned short*)(ws + o_ipl);
  unsigned short* oph = (unsigned short*)(ws + o_oph);
  unsigned short* opl = (unsigned short*)(ws + o_opl);
  unsigned short* ygh = (unsigned short*)(ws + o_ygh);
  unsigned short* ygl = (unsigned short*)(ws + o_ygl);

  embed_rms_k<<<NTOK,256,0,stream>>>(ids, emb, n0w, x, xnh, xnl);
  // split in_proj weights into bf16 hi/lo (lives in uconv slot until conv)
  split_bf_k<<<(4096*1024/8)/256,256,0,stream>>>(ipw, iph, ipl);
  // in_proj (split-bf16 MFMA): [2048,1024] x [4096,1024]^T -> proj [2048,4096]
  gemm_bfsplit_k<0><<<dim3(32,16),256,0,stream>>>(xnh, xnl, iph, ipl, proj, 4096, HD);
  conv_silu_k<<<(NTOK*INNER)/256,256,0,stream>>>(proj, cw, cb, uconv);
  // split out_proj weights (xn slot is dead now)
  split_bf_k<<<(1024*2048/8)/256,256,0,stream>>>(opw, oph, opl);
  // x_proj: [2048,2048] x [96,2048]^T -> xp [2048,96]
  gemm_f32k<0><<<dim3(2,32),256,0,stream>>>(uconv, INNER, xpw, xp, 96, 96, INNER, nullptr);
  // dt_proj + bias + softplus
  gemm_f32k<1><<<dim3(32,32),256,0,stream>>>(xp, 96, dtw, dl, INNER, INNER, DTR, dtb);
  scan_p1<<<dim3(8,NCH,2),256,0,stream>>>(dl, uconv, xp, alog, locfin, pst);
  scan_p2<<<dim3(8,SDIM,2),256,0,stream>>>(locfin, pst, initst);
  scan_p3<<<dim3(8,NCH,2),256,0,stream>>>(dl, uconv, xp, alog, dpar, initst, y);
  ygate_k<<<(NTOK*INNER)/256,256,0,stream>>>(y, proj, ygh, ygl);
  // out_proj + residual (split-bf16 MFMA): [2048,2048] x [1024,2048]^T -> x += ...
  gemm_bfsplit_k<2><<<dim3(8,16),256,0,stream>>>(ygh, ygl, oph, opl, x, HD, INNER);
  rms_router_k<<<NTOK,256,0,stream>>>(x, n1w, rw, rb, xnbf, ti, ts);
  route_build_k<<<1,256,0,stream>>>(ti, ts, slott, tslots, tile_e);
  // fc1: gathered xn (bf16) x fc1_w[e] -> h1 [5120,4096]
  gemm_bf16k<true,true><<<dim3(32,MAX_TILES),256,0,stream>>>(
      xnbf, HD, slott, f1w, 4096LL*1024LL, tile_e, h1, 4096, HD);
  silu_mul_k<<<(SLOT_CAP*FFN)/256,256,0,stream>>>(h1, hidden);
  // h1/proj span now dead -> convert emb to bf16 there for the LM head
  f2bf_arr_k<<<(VDIM*HD/8)/256,256,0,stream>>>(emb, embbf);
  // fc2: hidden (bf16) x fc2_w[e] -> eo [5120,1024]
  gemm_bf16k<false,true><<<dim3(8,MAX_TILES),256,0,stream>>>(
      hidden, FFN, nullptr, f2w, 1024LL*2048LL, tile_e, eo, HD, FFN);
  combine_rms_k<<<NTOK,256,0,stream>>>(x, eo, tslots, ts, fnw, xnf);
  // LM head: xnf (bf16) x embbf (bf16) -> out [2048,32000]
  lmhead_k<<<4000,256,0,stream>>>(xnf, embbf, out);
}